// Round 8
// baseline (720.148 us; speedup 1.0000x reference)
//
#include <hip/hip_runtime.h>
#include <math.h>

// Problem constants (fixed by reference)
#define N_NODES 50000
#define N_FEAT  500
#define DH      256
#define KC      16
#define NE      800000
#define KPAD    512     // N_FEAT padded to MFMA K multiple
#define MPAD    50048   // 391 * 128 (GEMM M tiles)
#define M2      (2 * MPAD)
#define SLICE_COLS 32   // cols per XCD slice (8 slices x 32 = 256)
#define JCOLS   8       // cols per job; job working set = 50048*8*2B = 0.8MB
#define RPB     192     // rows per spmm block (= blockDim, 1 row/lane)
#define NRB     261     // ceil(50000/192)
#define SPMM_BLOCKS (8 * NRB)
#define EDGE_CAP 4096   // LDS edge cache entries (32KB); mean 3072, sd ~55
#define POST_BLOCKS 2048

typedef __attribute__((ext_vector_type(8))) short short8;
typedef __attribute__((ext_vector_type(4))) float f32x4;

__device__ __forceinline__ unsigned short f2bf(float f) {
  unsigned u = __float_as_uint(f);
  u += 0x7FFFu + ((u >> 16) & 1u);   // RNE
  return (unsigned short)(u >> 16);
}

__device__ __forceinline__ float bf2f(unsigned short u) {
  return __uint_as_float((unsigned)u << 16);
}

__device__ __forceinline__ float selu_f(float x) {
  return 1.0507009873554805f * (x > 0.f ? x : 1.6732632423543772f * expm1f(x));
}

__device__ __forceinline__ void gload16(const void* g, void* l) {
  __builtin_amdgcn_global_load_lds(
      (const __attribute__((address_space(1))) unsigned int*)g,
      (__attribute__((address_space(3))) unsigned int*)l, 16, 0, 0);
}

// ---- f32 -> bf16 with zero padding (used only for W1) ----
__global__ void k_cvt_pad(const float* __restrict__ in, unsigned short* __restrict__ out,
                          int rin, int cin, int rout, int cout) {
  const int cquads = cout >> 2;
  const long total = (long)rout * cquads;
  for (long idx = (long)blockIdx.x * blockDim.x + threadIdx.x; idx < total;
       idx += (long)gridDim.x * blockDim.x) {
    const int row = (int)(idx / cquads);
    const int c4  = (int)(idx - (long)row * cquads) * 4;
    float x = 0.f, y = 0.f, z = 0.f, w = 0.f;
    if (row < rin && c4 < cin) {
      const float4 v = *(const float4*)(in + (size_t)row * cin + c4);
      x = v.x; y = v.y; z = v.z; w = v.w;
    }
    ushort4 o; o.x = f2bf(x); o.y = f2bf(y); o.z = f2bf(z); o.w = f2bf(w);
    *(ushort4*)(out + (size_t)row * cout + c4) = o;
  }
}

// ---- Fused f32->bf16 GEMM: out[m][n] = sum_k A[m][k]*W[n][k]
//      A = features (rows [0,MPAD)) or aug ([MPAD,2*MPAD)), f32 [N][500]
//      W = Wbf bf16 [256][512]; tile 128x256, 512 threads, 8 waves of 64x64.
//      Output: job-major XWs[job][node][8], job = isaug*32 + (col>>3),
//      so each SpMM job gathers from a contiguous, fully-utilized 0.8MB. ----
__global__ __launch_bounds__(512, 2) void k_gemm_fused(
    const float* __restrict__ Af, const float* __restrict__ Aa,
    const unsigned short* __restrict__ Wbf, unsigned short* __restrict__ XWs) {
  __shared__ short As[128 * 64];
  __shared__ short Bs[256 * 64];
  const int t = threadIdx.x;
  const int lane = t & 63, wave = t >> 6;
  const int wr = (wave >> 2) * 64, wc = (wave & 3) * 64;
  const int bm = blockIdx.x * 128;
  const bool isaug = bm >= MPAD;
  const float* __restrict__ src = isaug ? Aa : Af;
  const int row0 = isaug ? bm - MPAD : bm;
  const int lr = lane & 15, lk = (lane >> 4) * 8;
  const int ar = t >> 3, ac = (t & 7) * 8;
  f32x4 acc[4][4] = {};
  for (int kb = 0; kb < KPAD; kb += 64) {
#pragma unroll
    for (int i = 0; i < 4; ++i) {
      const int chunk = i * 512 + t;
      const int rb = chunk >> 3, sub = (chunk & 7) * 8;
      gload16(Wbf + (size_t)rb * KPAD + kb + sub, (void*)(Bs + (size_t)chunk * 8));
    }
#pragma unroll
    for (int h = 0; h < 128; h += 64) {
      const int gr = row0 + ar + h;
      const int c = kb + ac;
      const bool vr = gr < N_NODES;
      float4 u0 = {0.f, 0.f, 0.f, 0.f}, u1 = {0.f, 0.f, 0.f, 0.f};
      const float* arow = src + (size_t)gr * N_FEAT;
      if (vr && c < N_FEAT)     u0 = *(const float4*)(arow + c);
      if (vr && c + 4 < N_FEAT) u1 = *(const float4*)(arow + c + 4);
      short8 w;
      w[0] = (short)f2bf(u0.x); w[1] = (short)f2bf(u0.y);
      w[2] = (short)f2bf(u0.z); w[3] = (short)f2bf(u0.w);
      w[4] = (short)f2bf(u1.x); w[5] = (short)f2bf(u1.y);
      w[6] = (short)f2bf(u1.z); w[7] = (short)f2bf(u1.w);
      *(short8*)(As + (size_t)(ar + h) * 64 + ac) = w;
    }
    __syncthreads();
#pragma unroll
    for (int kk = 0; kk < 64; kk += 32) {
      short8 af[4], bfr[4];
#pragma unroll
      for (int mi = 0; mi < 4; ++mi)
        af[mi] = *(const short8*)(As + (wr + mi * 16 + lr) * 64 + kk + lk);
#pragma unroll
      for (int n = 0; n < 4; ++n)
        bfr[n] = *(const short8*)(Bs + (wc + n * 16 + lr) * 64 + kk + lk);
#pragma unroll
      for (int mi = 0; mi < 4; ++mi)
#pragma unroll
        for (int n = 0; n < 4; ++n)
          acc[mi][n] = __builtin_amdgcn_mfma_f32_16x16x32_bf16(af[mi], bfr[n], acc[mi][n], 0, 0, 0);
    }
    __syncthreads();
  }
  const int crow = (lane >> 4) * 4, ccol = lane & 15;
  const int phb = isaug ? 32 : 0;
#pragma unroll
  for (int mi = 0; mi < 4; ++mi)
#pragma unroll
    for (int n = 0; n < 4; ++n) {
      const int col = wc + n * 16 + ccol;
      const int job = phb + (col >> 3);
      const int cc = col & 7;
#pragma unroll
      for (int r = 0; r < 4; ++r) {
        const int node = row0 + wr + mi * 16 + crow + r;
        XWs[((size_t)job * MPAD + node) * JCOLS + cc] = f2bf(acc[mi][n][r]);
      }
    }
}

// ---- CSR build ----
__global__ void k_count(const int* __restrict__ row, int* __restrict__ counts) {
  const int e = blockIdx.x * blockDim.x + threadIdx.x;
  if (e < NE) atomicAdd(&counts[row[e]], 1);
}

__global__ __launch_bounds__(1024) void k_scan(const int* __restrict__ counts,
                                               int* __restrict__ row_ptr, int* __restrict__ cursor) {
  __shared__ int part[1024];
  const int t = threadIdx.x;
  const int per = (N_NODES + 1023) / 1024;
  const int base = t * per;
  int s = 0;
  for (int i = 0; i < per; ++i) { const int j = base + i; if (j < N_NODES) s += counts[j]; }
  part[t] = s;
  __syncthreads();
  for (int off = 1; off < 1024; off <<= 1) {
    const int v = (t >= off) ? part[t - off] : 0;
    __syncthreads();
    part[t] += v;
    __syncthreads();
  }
  int run = (t == 0) ? 0 : part[t - 1];
  for (int i = 0; i < per; ++i) {
    const int j = base + i;
    if (j < N_NODES) { row_ptr[j] = run; cursor[j] = run; run += counts[j]; }
  }
  if (t == 1023) row_ptr[N_NODES] = part[1023];
}

__global__ void k_scatter(const int* __restrict__ row, const int* __restrict__ col,
                          const float* __restrict__ gnv, int* __restrict__ cursor,
                          int* __restrict__ ecol, float* __restrict__ eval) {
  const int e = blockIdx.x * blockDim.x + threadIdx.x;
  if (e < NE) {
    const int p = atomicAdd(&cursor[row[e]], 1);
    ecol[p] = col[e];
    eval[p] = gnv[e];
  }
}

// ---- XCD-sliced SpMM + bias + selu -> O (bf16).
//      Block b: slice = b&7 (round-robin pins it to one XCD's L2),
//      rows [ (b>>3)*192, +192 ), one row per lane (192 threads).
//      Edges for the row range cached in LDS once (block-uniform global
//      fallback if >EDGE_CAP). 8 jobs = {feat,aug} x 4 col-groups of 8;
//      each job gathers 16B/edge from a contiguous 0.8MB job slice ->
//      L2-resident. 4-edge unrolled gathers for MLP. ----
__global__ __launch_bounds__(RPB, 3) void k_spmm_slice(
    const int* __restrict__ row_ptr, const int* __restrict__ ecol, const float* __restrict__ eval,
    const unsigned short* __restrict__ XWs, const float* __restrict__ b1,
    unsigned short* __restrict__ O) {
  __shared__ int   lci[EDGE_CAP];
  __shared__ float lcv[EDGE_CAP];
  const int slice = blockIdx.x & 7;
  const int rblk  = blockIdx.x >> 3;
  const int r0 = rblk * RPB;
  const int r1 = min(r0 + RPB, N_NODES);
  const int tid = threadIdx.x;
  const int ebase = row_ptr[r0];
  const int cnt   = row_ptr[r1] - ebase;
  const bool lpath = cnt <= EDGE_CAP;
  if (lpath) {
    for (int idx = tid; idx < cnt; idx += RPB) {
      lci[idx] = ecol[ebase + idx];
      lcv[idx] = eval[ebase + idx];
    }
  }
  const int row = r0 + tid;
  int s = 0, e = 0;
  if (row < r1) {
    s = row_ptr[row] - ebase;
    e = row_ptr[row + 1] - ebase;
  }
  __syncthreads();

  auto run_jobs = [&](auto loadc, auto loadv) {
    for (int ph = 0; ph < 2; ++ph) {
#pragma unroll
      for (int cg = 0; cg < 4; ++cg) {
        const int job = ph * 32 + slice * 4 + cg;
        const unsigned short* __restrict__ Xj = XWs + (size_t)job * MPAD * JCOLS;
        float acc[8] = {0.f, 0.f, 0.f, 0.f, 0.f, 0.f, 0.f, 0.f};
        int p = s;
        for (; p + 3 < e; p += 4) {
          const int   c0 = loadc(p),     c1 = loadc(p + 1);
          const int   c2 = loadc(p + 2), c3 = loadc(p + 3);
          const float v0 = loadv(p),     v1 = loadv(p + 1);
          const float v2 = loadv(p + 2), v3 = loadv(p + 3);
          const short8 x0 = *(const short8*)(Xj + (size_t)c0 * JCOLS);
          const short8 x1 = *(const short8*)(Xj + (size_t)c1 * JCOLS);
          const short8 x2 = *(const short8*)(Xj + (size_t)c2 * JCOLS);
          const short8 x3 = *(const short8*)(Xj + (size_t)c3 * JCOLS);
#pragma unroll
          for (int u = 0; u < 8; ++u) {
            acc[u] += v0 * bf2f((unsigned short)x0[u])
                    + v1 * bf2f((unsigned short)x1[u])
                    + v2 * bf2f((unsigned short)x2[u])
                    + v3 * bf2f((unsigned short)x3[u]);
          }
        }
        for (; p < e; ++p) {
          const int   c0 = loadc(p);
          const float v0 = loadv(p);
          const short8 x0 = *(const short8*)(Xj + (size_t)c0 * JCOLS);
#pragma unroll
          for (int u = 0; u < 8; ++u) acc[u] += v0 * bf2f((unsigned short)x0[u]);
        }
        const int gcol = slice * SLICE_COLS + cg * JCOLS;
        const float4 bl = *(const float4*)(b1 + gcol);
        const float4 bh = *(const float4*)(b1 + gcol + 4);
        short8 o;
        o[0] = (short)f2bf(selu_f(acc[0] + bl.x));
        o[1] = (short)f2bf(selu_f(acc[1] + bl.y));
        o[2] = (short)f2bf(selu_f(acc[2] + bl.z));
        o[3] = (short)f2bf(selu_f(acc[3] + bl.w));
        o[4] = (short)f2bf(selu_f(acc[4] + bh.x));
        o[5] = (short)f2bf(selu_f(acc[5] + bh.y));
        o[6] = (short)f2bf(selu_f(acc[6] + bh.z));
        o[7] = (short)f2bf(selu_f(acc[7] + bh.w));
        if (row < r1)
          *(short8*)(O + ((size_t)ph * N_NODES + row) * DH + gcol) = o;
      }
    }
  };

  if (lpath) {
    run_jobs([&](int p) { return lci[p]; }, [&](int p) { return lcv[p]; });
  } else {
    run_jobs([&](int p) { return ecol[ebase + p]; },
             [&](int p) { return eval[ebase + p]; });
  }
}

// ---- Epilogue over O: S softmax, exp-colsums, aug-colsums, dot, cluster sizes. ----
__global__ __launch_bounds__(256, 4) void k_post(
    const unsigned short* __restrict__ O, const float* __restrict__ Wt,
    const float* __restrict__ bt, float* __restrict__ S,
    float* __restrict__ exptot, float* __restrict__ augtot,
    float* __restrict__ csg, float* __restrict__ dotAG) {
  __shared__ float expacc[DH];
  __shared__ float augacc[DH];
  __shared__ float csacc[KC];
  __shared__ float dacc;
  expacc[threadIdx.x] = 0.f;
  augacc[threadIdx.x] = 0.f;
  if (threadIdx.x < KC) csacc[threadIdx.x] = 0.f;
  if (threadIdx.x == 0) dacc = 0.f;
  __syncthreads();

  const int wave = threadIdx.x >> 6, lane = threadIdx.x & 63;
  const int c0 = lane * 4;
  const unsigned short* Of = O;
  const unsigned short* Oa = O + (size_t)N_NODES * DH;

  float lexp[4] = {0.f, 0.f, 0.f, 0.f};
  float laug[4] = {0.f, 0.f, 0.f, 0.f};
  float ldot = 0.f, lcs = 0.f;
  const float btk = (lane < KC) ? bt[lane] : 0.f;

  for (int i = blockIdx.x * 4 + wave; i < N_NODES; i += POST_BLOCKS * 4) {
    const ushort4 fu = *(const ushort4*)(Of + (size_t)i * DH + c0);
    const ushort4 au = *(const ushort4*)(Oa + (size_t)i * DH + c0);
    const float of[4] = {bf2f(fu.x), bf2f(fu.y), bf2f(fu.z), bf2f(fu.w)};
    const float oa[4] = {bf2f(au.x), bf2f(au.y), bf2f(au.z), bf2f(au.w)};
#pragma unroll
    for (int u = 0; u < 4; ++u) {
      lexp[u] += expf(of[u]);
      laug[u] += oa[u];
      ldot += of[u] * oa[u];
    }
    float lg[KC];
#pragma unroll
    for (int k = 0; k < KC; ++k) {
      const float4 w = *(const float4*)(Wt + (size_t)k * DH + c0);
      lg[k] = of[0] * w.x + of[1] * w.y + of[2] * w.z + of[3] * w.w;
    }
#pragma unroll
    for (int off = 32; off; off >>= 1)
#pragma unroll
      for (int k = 0; k < KC; ++k) lg[k] += __shfl_xor(lg[k], off);
    float mx = -3.4e38f;
    float se = 0.f;
#pragma unroll
    for (int k = 0; k < KC; ++k) lg[k] += __shfl(btk, k);
#pragma unroll
    for (int k = 0; k < KC; ++k) mx = fmaxf(mx, lg[k]);
#pragma unroll
    for (int k = 0; k < KC; ++k) { lg[k] = expf(lg[k] - mx); se += lg[k]; }
    const float inv = 1.f / se;
    float myv = 0.f;
#pragma unroll
    for (int k = 0; k < KC; ++k) if (lane == k) myv = lg[k];
    if (lane < KC) {
      const float sv = myv * inv;
      S[(size_t)i * KC + lane] = sv;
      lcs += sv;
    }
  }

#pragma unroll
  for (int off = 32; off; off >>= 1) ldot += __shfl_xor(ldot, off);
  if (lane == 0) atomicAdd(&dacc, ldot);
#pragma unroll
  for (int u = 0; u < 4; ++u) {
    atomicAdd(&expacc[c0 + u], lexp[u]);
    atomicAdd(&augacc[c0 + u], laug[u]);
  }
  if (lane < KC) atomicAdd(&csacc[lane], lcs);
  __syncthreads();
  atomicAdd(&exptot[threadIdx.x], expacc[threadIdx.x]);
  atomicAdd(&augtot[threadIdx.x], augacc[threadIdx.x]);
  if (threadIdx.x < KC) atomicAdd(&csg[threadIdx.x], csacc[threadIdx.x]);
  if (threadIdx.x == 0) atomicAdd(dotAG, dacc);
}

// ---- edge stats: tp = sum_e v*dot16(S[row],S[col]); nl[k] = sum_e v*S[col,k] ----
__global__ __launch_bounds__(256) void k_edge(const int* __restrict__ grow, const int* __restrict__ gcol,
                                              const float* __restrict__ gvals, const float* __restrict__ S,
                                              float* __restrict__ nl, float* __restrict__ tp) {
  float ltp = 0.f;
  float lnl[KC];
#pragma unroll
  for (int k = 0; k < KC; ++k) lnl[k] = 0.f;
  for (long e = (long)blockIdx.x * 256 + threadIdx.x; e < NE; e += (long)gridDim.x * 256) {
    const int r = grow[e], c = gcol[e];
    const float v = gvals[e];
    const float4* sr = (const float4*)(S + (size_t)r * KC);
    const float4* sc = (const float4*)(S + (size_t)c * KC);
    const float4 a0 = sr[0], a1 = sr[1], a2 = sr[2], a3 = sr[3];
    const float4 b0 = sc[0], b1v = sc[1], b2 = sc[2], b3 = sc[3];
    const float dot = a0.x * b0.x + a0.y * b0.y + a0.z * b0.z + a0.w * b0.w
                    + a1.x * b1v.x + a1.y * b1v.y + a1.z * b1v.z + a1.w * b1v.w
                    + a2.x * b2.x + a2.y * b2.y + a2.z * b2.z + a2.w * b2.w
                    + a3.x * b3.x + a3.y * b3.y + a3.z * b3.z + a3.w * b3.w;
    ltp += v * dot;
    lnl[0] += v * b0.x;  lnl[1] += v * b0.y;  lnl[2] += v * b0.z;  lnl[3] += v * b0.w;
    lnl[4] += v * b1v.x; lnl[5] += v * b1v.y; lnl[6] += v * b1v.z; lnl[7] += v * b1v.w;
    lnl[8] += v * b2.x;  lnl[9] += v * b2.y;  lnl[10] += v * b2.z; lnl[11] += v * b2.w;
    lnl[12] += v * b3.x; lnl[13] += v * b3.y; lnl[14] += v * b3.z; lnl[15] += v * b3.w;
  }
#pragma unroll
  for (int off = 32; off; off >>= 1) {
    ltp += __shfl_xor(ltp, off);
#pragma unroll
    for (int k = 0; k < KC; ++k) lnl[k] += __shfl_xor(lnl[k], off);
  }
  __shared__ float wred[4][KC + 1];
  const int wave = threadIdx.x >> 6, lane = threadIdx.x & 63;
  if (lane == 0) {
    wred[wave][0] = ltp;
#pragma unroll
    for (int k = 0; k < KC; ++k) wred[wave][1 + k] = lnl[k];
  }
  __syncthreads();
  if (threadIdx.x < KC + 1) {
    const float s = wred[0][threadIdx.x] + wred[1][threadIdx.x] + wred[2][threadIdx.x] + wred[3][threadIdx.x];
    if (threadIdx.x == 0) atomicAdd(tp, s);
    else atomicAdd(&nl[threadIdx.x - 1], s);
  }
}

// ---- final scalar assembly ----
// scal layout: [0]=dotAG, [1]=tp, [2..17]=nl, [18..33]=cs
__global__ void k_final(const float* __restrict__ exptot, const float* __restrict__ augtot,
                        const float* __restrict__ scal, float* __restrict__ out) {
  const int d = threadIdx.x;
  const float L = logf(exptot[d]);
  const float sa = augtot[d];
  __shared__ float red[DH];
  red[d] = L * sa;
  __syncthreads();
  for (int off = 128; off; off >>= 1) {
    if (d < off) red[d] += red[d + off];
    __syncthreads();
  }
  if (d == 0) {
    const float sumLA = red[0];
    const float dotAG = scal[0];
    const float tp = scal[1];
    float nl2 = 0.f, cs2 = 0.f;
#pragma unroll
    for (int k = 0; k < KC; ++k) {
      nl2 += scal[2 + k] * scal[2 + k];
      cs2 += scal[18 + k] * scal[18 + k];
    }
    const float fE = (float)NE;
    const float con = -(dotAG - sumLA) / (float)DH;
    const float trn = nl2 / (2.f * fE);
    const float spectral = -(tp - trn) / (2.f * fE);
    const float cluster = (sqrtf(cs2) / (float)N_NODES * 4.f - 1.f);
    out[0] = spectral + cluster + 0.5f * con;
  }
}

extern "C" void kernel_launch(void* const* d_in, const int* in_sizes, int n_in,
                              void* d_out, int out_size, void* d_ws, size_t ws_size,
                              hipStream_t stream) {
  const float* features = (const float*)d_in[0];
  const float* augf     = (const float*)d_in[1];
  const int*   grow     = (const int*)d_in[2];
  const int*   gcol     = (const int*)d_in[3];
  const float* gvals    = (const float*)d_in[4];
  const float* gnv      = (const float*)d_in[5];
  const float* W1       = (const float*)d_in[8];
  const float* b1       = (const float*)d_in[9];
  const float* Wt       = (const float*)d_in[10];
  const float* bt       = (const float*)d_in[11];

  char* ws = (char*)d_ws;
  size_t off = 0;
  auto alloc = [&](size_t bytes) -> void* {
    void* p = ws + off;
    off = (off + bytes + 255) & ~(size_t)255;
    return p;
  };
  unsigned short* Wbf  = (unsigned short*)alloc((size_t)DH * KPAD * 2);
  unsigned short* XWs  = (unsigned short*)alloc((size_t)64 * MPAD * JCOLS * 2);
  unsigned short* O    = (unsigned short*)alloc((size_t)2 * N_NODES * DH * 2);
  float* S       = (float*)alloc((size_t)N_NODES * KC * 4);
  int*   ecol    = (int*)alloc((size_t)NE * 4);
  float* eval    = (float*)alloc((size_t)NE * 4);
  int*   row_ptr = (int*)alloc((size_t)(N_NODES + 1) * 4);
  int*   cursor  = (int*)alloc((size_t)N_NODES * 4);
  int*   counts  = (int*)alloc((size_t)N_NODES * 4);
  float* exptot  = (float*)alloc((size_t)DH * 4);   // contiguous zero region:
  float* augtot  = (float*)alloc((size_t)DH * 4);   //   exptot | augtot | scal
  float* scal    = (float*)alloc(64 * 4);
  if (off > ws_size) return;  // workspace too small: fail loudly, no OOB

  hipMemsetAsync(counts, 0, (size_t)N_NODES * 4, stream);
  hipMemsetAsync(exptot, 0, (size_t)DH * 4 * 2 + 64 * 4, stream);

  // W1 -> bf16 (tiny)
  k_cvt_pad<<<128, 256, 0, stream>>>(W1, Wbf, DH, N_FEAT, DH, KPAD);

  // CSR build
  k_count<<<(NE + 255) / 256, 256, 0, stream>>>(grow, counts);
  k_scan<<<1, 1024, 0, stream>>>(counts, row_ptr, cursor);
  k_scatter<<<(NE + 255) / 256, 256, 0, stream>>>(grow, gcol, gnv, cursor, ecol, eval);

  // fused-conversion GEMM over both matrices -> job-major XWs
  k_gemm_fused<<<M2 / 128, 512, 0, stream>>>(features, augf, Wbf, XWs);

  // XCD-sliced SpMM (+bias+selu) -> O bf16
  k_spmm_slice<<<SPMM_BLOCKS, RPB, 0, stream>>>(row_ptr, ecol, eval, XWs, b1, O);

  // epilogue: S softmax + global partials
  k_post<<<POST_BLOCKS, 256, 0, stream>>>(O, Wt, bt, S, exptot, augtot,
                                          scal + 18, scal + 0);

  // graph stats on assignments
  k_edge<<<512, 256, 0, stream>>>(grow, gcol, gvals, S, scal + 2, scal + 1);

  // final scalar
  k_final<<<1, 256, 0, stream>>>(exptot, augtot, scal, (float*)d_out);
}

// Round 9
// 652.382 us; speedup vs baseline: 1.1039x; 1.1039x over previous
//
#include <hip/hip_runtime.h>
#include <math.h>

// Problem constants (fixed by reference)
#define N_NODES 50000
#define N_FEAT  500
#define DH      256
#define KC      16
#define NE      800000
#define KPAD    512     // N_FEAT padded to MFMA K multiple
#define MPAD    50048   // 391 * 128 (GEMM M tiles)
#define M2      (2 * MPAD)
#define SLICE_COLS 32   // D-slice per XCD: 50048*32*2B = 3.2MB fits 4MB L2
#define NPAIR   8       // 8 col-slices per matrix
#define SPMM_BLOCKS 2048
#define ROWS_PER_BLK 196  // ceil(50000/256)
#define POST_BLOCKS 2048

typedef __attribute__((ext_vector_type(8))) short short8;
typedef __attribute__((ext_vector_type(4))) float f32x4;

__device__ __forceinline__ unsigned short f2bf(float f) {
  unsigned u = __float_as_uint(f);
  u += 0x7FFFu + ((u >> 16) & 1u);   // RNE
  return (unsigned short)(u >> 16);
}

__device__ __forceinline__ float bf2f(unsigned short u) {
  return __uint_as_float((unsigned)u << 16);
}

__device__ __forceinline__ float selu_f(float x) {
  return 1.0507009873554805f * (x > 0.f ? x : 1.6732632423543772f * expm1f(x));
}

__device__ __forceinline__ void gload16(const void* g, void* l) {
  __builtin_amdgcn_global_load_lds(
      (const __attribute__((address_space(1))) unsigned int*)g,
      (__attribute__((address_space(3))) unsigned int*)l, 16, 0, 0);
}

// ---- f32 -> bf16 with zero padding (used only for W1) ----
__global__ void k_cvt_pad(const float* __restrict__ in, unsigned short* __restrict__ out,
                          int rin, int cin, int rout, int cout) {
  const int cquads = cout >> 2;
  const long total = (long)rout * cquads;
  for (long idx = (long)blockIdx.x * blockDim.x + threadIdx.x; idx < total;
       idx += (long)gridDim.x * blockDim.x) {
    const int row = (int)(idx / cquads);
    const int c4  = (int)(idx - (long)row * cquads) * 4;
    float x = 0.f, y = 0.f, z = 0.f, w = 0.f;
    if (row < rin && c4 < cin) {
      const float4 v = *(const float4*)(in + (size_t)row * cin + c4);
      x = v.x; y = v.y; z = v.z; w = v.w;
    }
    ushort4 o; o.x = f2bf(x); o.y = f2bf(y); o.z = f2bf(z); o.w = f2bf(w);
    *(ushort4*)(out + (size_t)row * cout + c4) = o;
  }
}

// ---- Fused f32->bf16 GEMM: out[m][n] = sum_k A[m][k]*W[n][k]
//      A = features (rows [0,MPAD)) or aug ([MPAD,2*MPAD)), f32 [N][500]
//      W = Wbf bf16 [256][512]; tile 128x256, 512 threads, 8 waves of 64x64.
//      Output: slice-major XWs[pair][node][32], pair = isaug*8 + (col>>5).
//      C-write staged through As (free after K-loop) in 4 passes of 64 cols
//      -> coalesced 16B stores (vs 25.6M scalar 2B scattered stores). ----
__global__ __launch_bounds__(512, 2) void k_gemm_fused(
    const float* __restrict__ Af, const float* __restrict__ Aa,
    const unsigned short* __restrict__ Wbf, unsigned short* __restrict__ XWs) {
  __shared__ short As[128 * 64];
  __shared__ short Bs[256 * 64];
  const int t = threadIdx.x;
  const int lane = t & 63, wave = t >> 6;
  const int wr = (wave >> 2) * 64, wc = (wave & 3) * 64;
  const int bm = blockIdx.x * 128;
  const bool isaug = bm >= MPAD;
  const float* __restrict__ src = isaug ? Aa : Af;
  const int row0 = isaug ? bm - MPAD : bm;
  const int lr = lane & 15, lk = (lane >> 4) * 8;
  const int ar = t >> 3, ac = (t & 7) * 8;
  f32x4 acc[4][4] = {};
  for (int kb = 0; kb < KPAD; kb += 64) {
#pragma unroll
    for (int i = 0; i < 4; ++i) {
      const int chunk = i * 512 + t;
      const int rb = chunk >> 3, sub = (chunk & 7) * 8;
      gload16(Wbf + (size_t)rb * KPAD + kb + sub, (void*)(Bs + (size_t)chunk * 8));
    }
#pragma unroll
    for (int h = 0; h < 128; h += 64) {
      const int gr = row0 + ar + h;
      const int c = kb + ac;
      const bool vr = gr < N_NODES;
      float4 u0 = {0.f, 0.f, 0.f, 0.f}, u1 = {0.f, 0.f, 0.f, 0.f};
      const float* arow = src + (size_t)gr * N_FEAT;
      if (vr && c < N_FEAT)     u0 = *(const float4*)(arow + c);
      if (vr && c + 4 < N_FEAT) u1 = *(const float4*)(arow + c + 4);
      short8 w;
      w[0] = (short)f2bf(u0.x); w[1] = (short)f2bf(u0.y);
      w[2] = (short)f2bf(u0.z); w[3] = (short)f2bf(u0.w);
      w[4] = (short)f2bf(u1.x); w[5] = (short)f2bf(u1.y);
      w[6] = (short)f2bf(u1.z); w[7] = (short)f2bf(u1.w);
      *(short8*)(As + (size_t)(ar + h) * 64 + ac) = w;
    }
    __syncthreads();
#pragma unroll
    for (int kk = 0; kk < 64; kk += 32) {
      short8 af[4], bfr[4];
#pragma unroll
      for (int mi = 0; mi < 4; ++mi)
        af[mi] = *(const short8*)(As + (wr + mi * 16 + lr) * 64 + kk + lk);
#pragma unroll
      for (int n = 0; n < 4; ++n)
        bfr[n] = *(const short8*)(Bs + (wc + n * 16 + lr) * 64 + kk + lk);
#pragma unroll
      for (int mi = 0; mi < 4; ++mi)
#pragma unroll
        for (int n = 0; n < 4; ++n)
          acc[mi][n] = __builtin_amdgcn_mfma_f32_16x16x32_bf16(af[mi], bfr[n], acc[mi][n], 0, 0, 0);
    }
    __syncthreads();
  }
  // ---- coalesced C-write: 4 passes of 64 cols via As ----
  const int crow = (lane >> 4) * 4, ccol = lane & 15;
  const int phb8 = isaug ? NPAIR : 0;
  const int snode = t >> 2, ssub = t & 3;   // 128 nodes x 4 16B-chunks
#pragma unroll
  for (int cb = 0; cb < 4; ++cb) {
    if ((wave & 3) == cb) {   // the 2 waves owning cols [cb*64, cb*64+64)
#pragma unroll
      for (int mi = 0; mi < 4; ++mi)
#pragma unroll
        for (int n = 0; n < 4; ++n)
#pragma unroll
          for (int r = 0; r < 4; ++r)
            As[(wr + mi * 16 + crow + r) * 64 + n * 16 + ccol] =
                (short)f2bf(acc[mi][n][r]);
    }
    __syncthreads();
#pragma unroll
    for (int p2 = 0; p2 < 2; ++p2) {
      const int pair = phb8 + cb * 2 + p2;
      const short8 vv = *(const short8*)(As + snode * 64 + p2 * 32 + ssub * 8);
      *(short8*)(XWs + ((size_t)pair * MPAD + row0 + snode) * SLICE_COLS + ssub * 8) = vv;
    }
    __syncthreads();
  }
}

// ---- CSR build ----
__global__ void k_count(const int* __restrict__ row, int* __restrict__ counts) {
  const int e = blockIdx.x * blockDim.x + threadIdx.x;
  if (e < NE) atomicAdd(&counts[row[e]], 1);
}

__global__ __launch_bounds__(1024) void k_scan(const int* __restrict__ counts,
                                               int* __restrict__ row_ptr, int* __restrict__ cursor) {
  __shared__ int part[1024];
  const int t = threadIdx.x;
  const int per = (N_NODES + 1023) / 1024;
  const int base = t * per;
  int s = 0;
  for (int i = 0; i < per; ++i) { const int j = base + i; if (j < N_NODES) s += counts[j]; }
  part[t] = s;
  __syncthreads();
  for (int off = 1; off < 1024; off <<= 1) {
    const int v = (t >= off) ? part[t - off] : 0;
    __syncthreads();
    part[t] += v;
    __syncthreads();
  }
  int run = (t == 0) ? 0 : part[t - 1];
  for (int i = 0; i < per; ++i) {
    const int j = base + i;
    if (j < N_NODES) { row_ptr[j] = run; cursor[j] = run; run += counts[j]; }
  }
  if (t == 1023) row_ptr[N_NODES] = part[1023];
}

__global__ void k_scatter(const int* __restrict__ row, const int* __restrict__ col,
                          const float* __restrict__ gnv, int* __restrict__ cursor,
                          int* __restrict__ ecol, float* __restrict__ eval) {
  const int e = blockIdx.x * blockDim.x + threadIdx.x;
  if (e < NE) {
    const int p = atomicAdd(&cursor[row[e]], 1);
    ecol[p] = col[e];
    eval[p] = gnv[e];
  }
}

// ---- XCD-sliced SpMM + bias + selu -> O (bf16). ONE PHASE per launch so
//      each XCD's gather working set is a single 3.2MB slice (R7 looped both
//      phases in-block -> 6.4MB > 4MB L2 -> 422MB FETCH thrash).
//      Block b: slice = b&7 (round-robin pins to XCD), rows [(b>>3)*196,+196).
//      4-lane group per row; lane covers 8 cols; group reads one full 64B line
//      per edge. No LDS, no atomics, ~28 VGPR. ----
__global__ __launch_bounds__(256, 4) void k_spmm_slice(
    const int* __restrict__ row_ptr, const int* __restrict__ ecol, const float* __restrict__ eval,
    const unsigned short* __restrict__ XWp,  // phase base: XWs + ph*8*MPAD*32
    const float* __restrict__ b1,
    unsigned short* __restrict__ Ob) {       // phase base: O + ph*N*DH
  const int slice = blockIdx.x & 7;
  const int rblk  = blockIdx.x >> 3;
  const int r0 = rblk * ROWS_PER_BLK;
  const int r1 = min(r0 + ROWS_PER_BLK, N_NODES);
  const int wave = threadIdx.x >> 6, lane = threadIdx.x & 63;
  const int g = lane >> 2, sub = lane & 3;
  const int scol = slice * SLICE_COLS + sub * 8;

  const float4 b0 = *(const float4*)(b1 + scol);
  const float4 b4 = *(const float4*)(b1 + scol + 4);
  const unsigned short* __restrict__ Xb =
      XWp + (size_t)slice * MPAD * SLICE_COLS + sub * 8;

  for (int rb = r0; rb < r1; rb += 64) {
    const int row = rb + wave * 16 + g;
    if (row >= r1) continue;
    const int s = row_ptr[row], e = row_ptr[row + 1];
    float acc[8] = {0.f, 0.f, 0.f, 0.f, 0.f, 0.f, 0.f, 0.f};
    int p = s;
    for (; p + 1 < e; p += 2) {
      const int   c0 = ecol[p],  c1 = ecol[p + 1];
      const float v0 = eval[p],  v1 = eval[p + 1];
      const short8 x0 = *(const short8*)(Xb + (size_t)c0 * SLICE_COLS);
      const short8 x1 = *(const short8*)(Xb + (size_t)c1 * SLICE_COLS);
#pragma unroll
      for (int u = 0; u < 8; ++u) {
        acc[u] += v0 * bf2f((unsigned short)x0[u]);
        acc[u] += v1 * bf2f((unsigned short)x1[u]);
      }
    }
    if (p < e) {
      const int   c0 = ecol[p];
      const float v0 = eval[p];
      const short8 x0 = *(const short8*)(Xb + (size_t)c0 * SLICE_COLS);
#pragma unroll
      for (int u = 0; u < 8; ++u) acc[u] += v0 * bf2f((unsigned short)x0[u]);
    }
    short8 o;
    o[0] = (short)f2bf(selu_f(acc[0] + b0.x));
    o[1] = (short)f2bf(selu_f(acc[1] + b0.y));
    o[2] = (short)f2bf(selu_f(acc[2] + b0.z));
    o[3] = (short)f2bf(selu_f(acc[3] + b0.w));
    o[4] = (short)f2bf(selu_f(acc[4] + b4.x));
    o[5] = (short)f2bf(selu_f(acc[5] + b4.y));
    o[6] = (short)f2bf(selu_f(acc[6] + b4.z));
    o[7] = (short)f2bf(selu_f(acc[7] + b4.w));
    *(short8*)(Ob + (size_t)row * DH + scol) = o;
  }
}

// ---- Epilogue over O: S softmax, exp-colsums, aug-colsums, dot, cluster sizes. ----
__global__ __launch_bounds__(256, 4) void k_post(
    const unsigned short* __restrict__ O, const float* __restrict__ Wt,
    const float* __restrict__ bt, float* __restrict__ S,
    float* __restrict__ exptot, float* __restrict__ augtot,
    float* __restrict__ csg, float* __restrict__ dotAG) {
  __shared__ float expacc[DH];
  __shared__ float augacc[DH];
  __shared__ float csacc[KC];
  __shared__ float dacc;
  expacc[threadIdx.x] = 0.f;
  augacc[threadIdx.x] = 0.f;
  if (threadIdx.x < KC) csacc[threadIdx.x] = 0.f;
  if (threadIdx.x == 0) dacc = 0.f;
  __syncthreads();

  const int wave = threadIdx.x >> 6, lane = threadIdx.x & 63;
  const int c0 = lane * 4;
  const unsigned short* Of = O;
  const unsigned short* Oa = O + (size_t)N_NODES * DH;

  float lexp[4] = {0.f, 0.f, 0.f, 0.f};
  float laug[4] = {0.f, 0.f, 0.f, 0.f};
  float ldot = 0.f, lcs = 0.f;
  const float btk = (lane < KC) ? bt[lane] : 0.f;

  for (int i = blockIdx.x * 4 + wave; i < N_NODES; i += POST_BLOCKS * 4) {
    const ushort4 fu = *(const ushort4*)(Of + (size_t)i * DH + c0);
    const ushort4 au = *(const ushort4*)(Oa + (size_t)i * DH + c0);
    const float of[4] = {bf2f(fu.x), bf2f(fu.y), bf2f(fu.z), bf2f(fu.w)};
    const float oa[4] = {bf2f(au.x), bf2f(au.y), bf2f(au.z), bf2f(au.w)};
#pragma unroll
    for (int u = 0; u < 4; ++u) {
      lexp[u] += expf(of[u]);
      laug[u] += oa[u];
      ldot += of[u] * oa[u];
    }
    float lg[KC];
#pragma unroll
    for (int k = 0; k < KC; ++k) {
      const float4 w = *(const float4*)(Wt + (size_t)k * DH + c0);
      lg[k] = of[0] * w.x + of[1] * w.y + of[2] * w.z + of[3] * w.w;
    }
#pragma unroll
    for (int off = 32; off; off >>= 1)
#pragma unroll
      for (int k = 0; k < KC; ++k) lg[k] += __shfl_xor(lg[k], off);
    float mx = -3.4e38f;
    float se = 0.f;
#pragma unroll
    for (int k = 0; k < KC; ++k) lg[k] += __shfl(btk, k);
#pragma unroll
    for (int k = 0; k < KC; ++k) mx = fmaxf(mx, lg[k]);
#pragma unroll
    for (int k = 0; k < KC; ++k) { lg[k] = expf(lg[k] - mx); se += lg[k]; }
    const float inv = 1.f / se;
    float myv = 0.f;
#pragma unroll
    for (int k = 0; k < KC; ++k) if (lane == k) myv = lg[k];
    if (lane < KC) {
      const float sv = myv * inv;
      S[(size_t)i * KC + lane] = sv;
      lcs += sv;
    }
  }

#pragma unroll
  for (int off = 32; off; off >>= 1) ldot += __shfl_xor(ldot, off);
  if (lane == 0) atomicAdd(&dacc, ldot);
#pragma unroll
  for (int u = 0; u < 4; ++u) {
    atomicAdd(&expacc[c0 + u], lexp[u]);
    atomicAdd(&augacc[c0 + u], laug[u]);
  }
  if (lane < KC) atomicAdd(&csacc[lane], lcs);
  __syncthreads();
  atomicAdd(&exptot[threadIdx.x], expacc[threadIdx.x]);
  atomicAdd(&augtot[threadIdx.x], augacc[threadIdx.x]);
  if (threadIdx.x < KC) atomicAdd(&csg[threadIdx.x], csacc[threadIdx.x]);
  if (threadIdx.x == 0) atomicAdd(dotAG, dacc);
}

// ---- edge stats: tp = sum_e v*dot16(S[row],S[col]); nl[k] = sum_e v*S[col,k] ----
__global__ __launch_bounds__(256) void k_edge(const int* __restrict__ grow, const int* __restrict__ gcol,
                                              const float* __restrict__ gvals, const float* __restrict__ S,
                                              float* __restrict__ nl, float* __restrict__ tp) {
  float ltp = 0.f;
  float lnl[KC];
#pragma unroll
  for (int k = 0; k < KC; ++k) lnl[k] = 0.f;
  for (long e = (long)blockIdx.x * 256 + threadIdx.x; e < NE; e += (long)gridDim.x * 256) {
    const int r = grow[e], c = gcol[e];
    const float v = gvals[e];
    const float4* sr = (const float4*)(S + (size_t)r * KC);
    const float4* sc = (const float4*)(S + (size_t)c * KC);
    const float4 a0 = sr[0], a1 = sr[1], a2 = sr[2], a3 = sr[3];
    const float4 b0 = sc[0], b1v = sc[1], b2 = sc[2], b3 = sc[3];
    const float dot = a0.x * b0.x + a0.y * b0.y + a0.z * b0.z + a0.w * b0.w
                    + a1.x * b1v.x + a1.y * b1v.y + a1.z * b1v.z + a1.w * b1v.w
                    + a2.x * b2.x + a2.y * b2.y + a2.z * b2.z + a2.w * b2.w
                    + a3.x * b3.x + a3.y * b3.y + a3.z * b3.z + a3.w * b3.w;
    ltp += v * dot;
    lnl[0] += v * b0.x;  lnl[1] += v * b0.y;  lnl[2] += v * b0.z;  lnl[3] += v * b0.w;
    lnl[4] += v * b1v.x; lnl[5] += v * b1v.y; lnl[6] += v * b1v.z; lnl[7] += v * b1v.w;
    lnl[8] += v * b2.x;  lnl[9] += v * b2.y;  lnl[10] += v * b2.z; lnl[11] += v * b2.w;
    lnl[12] += v * b3.x; lnl[13] += v * b3.y; lnl[14] += v * b3.z; lnl[15] += v * b3.w;
  }
#pragma unroll
  for (int off = 32; off; off >>= 1) {
    ltp += __shfl_xor(ltp, off);
#pragma unroll
    for (int k = 0; k < KC; ++k) lnl[k] += __shfl_xor(lnl[k], off);
  }
  __shared__ float wred[4][KC + 1];
  const int wave = threadIdx.x >> 6, lane = threadIdx.x & 63;
  if (lane == 0) {
    wred[wave][0] = ltp;
#pragma unroll
    for (int k = 0; k < KC; ++k) wred[wave][1 + k] = lnl[k];
  }
  __syncthreads();
  if (threadIdx.x < KC + 1) {
    const float s = wred[0][threadIdx.x] + wred[1][threadIdx.x] + wred[2][threadIdx.x] + wred[3][threadIdx.x];
    if (threadIdx.x == 0) atomicAdd(tp, s);
    else atomicAdd(&nl[threadIdx.x - 1], s);
  }
}

// ---- final scalar assembly ----
// scal layout: [0]=dotAG, [1]=tp, [2..17]=nl, [18..33]=cs
__global__ void k_final(const float* __restrict__ exptot, const float* __restrict__ augtot,
                        const float* __restrict__ scal, float* __restrict__ out) {
  const int d = threadIdx.x;
  const float L = logf(exptot[d]);
  const float sa = augtot[d];
  __shared__ float red[DH];
  red[d] = L * sa;
  __syncthreads();
  for (int off = 128; off; off >>= 1) {
    if (d < off) red[d] += red[d + off];
    __syncthreads();
  }
  if (d == 0) {
    const float sumLA = red[0];
    const float dotAG = scal[0];
    const float tp = scal[1];
    float nl2 = 0.f, cs2 = 0.f;
#pragma unroll
    for (int k = 0; k < KC; ++k) {
      nl2 += scal[2 + k] * scal[2 + k];
      cs2 += scal[18 + k] * scal[18 + k];
    }
    const float fE = (float)NE;
    const float con = -(dotAG - sumLA) / (float)DH;
    const float trn = nl2 / (2.f * fE);
    const float spectral = -(tp - trn) / (2.f * fE);
    const float cluster = (sqrtf(cs2) / (float)N_NODES * 4.f - 1.f);
    out[0] = spectral + cluster + 0.5f * con;
  }
}

extern "C" void kernel_launch(void* const* d_in, const int* in_sizes, int n_in,
                              void* d_out, int out_size, void* d_ws, size_t ws_size,
                              hipStream_t stream) {
  const float* features = (const float*)d_in[0];
  const float* augf     = (const float*)d_in[1];
  const int*   grow     = (const int*)d_in[2];
  const int*   gcol     = (const int*)d_in[3];
  const float* gvals    = (const float*)d_in[4];
  const float* gnv      = (const float*)d_in[5];
  const float* W1       = (const float*)d_in[8];
  const float* b1       = (const float*)d_in[9];
  const float* Wt       = (const float*)d_in[10];
  const float* bt       = (const float*)d_in[11];

  char* ws = (char*)d_ws;
  size_t off = 0;
  auto alloc = [&](size_t bytes) -> void* {
    void* p = ws + off;
    off = (off + bytes + 255) & ~(size_t)255;
    return p;
  };
  unsigned short* Wbf  = (unsigned short*)alloc((size_t)DH * KPAD * 2);
  unsigned short* XWs  = (unsigned short*)alloc((size_t)16 * MPAD * SLICE_COLS * 2);
  unsigned short* O    = (unsigned short*)alloc((size_t)2 * N_NODES * DH * 2);
  float* S       = (float*)alloc((size_t)N_NODES * KC * 4);
  int*   ecol    = (int*)alloc((size_t)NE * 4);
  float* eval    = (float*)alloc((size_t)NE * 4);
  int*   row_ptr = (int*)alloc((size_t)(N_NODES + 1) * 4);
  int*   cursor  = (int*)alloc((size_t)N_NODES * 4);
  int*   counts  = (int*)alloc((size_t)N_NODES * 4);
  float* exptot  = (float*)alloc((size_t)DH * 4);   // contiguous zero region:
  float* augtot  = (float*)alloc((size_t)DH * 4);   //   exptot | augtot | scal
  float* scal    = (float*)alloc(64 * 4);
  if (off > ws_size) return;  // workspace too small: fail loudly, no OOB

  hipMemsetAsync(counts, 0, (size_t)N_NODES * 4, stream);
  hipMemsetAsync(exptot, 0, (size_t)DH * 4 * 2 + 64 * 4, stream);

  // W1 -> bf16 (tiny)
  k_cvt_pad<<<128, 256, 0, stream>>>(W1, Wbf, DH, N_FEAT, DH, KPAD);

  // CSR build
  k_count<<<(NE + 255) / 256, 256, 0, stream>>>(grow, counts);
  k_scan<<<1, 1024, 0, stream>>>(counts, row_ptr, cursor);
  k_scatter<<<(NE + 255) / 256, 256, 0, stream>>>(grow, gcol, gnv, cursor, ecol, eval);

  // fused-conversion GEMM over both matrices -> slice-major XWs (coalesced C)
  k_gemm_fused<<<M2 / 128, 512, 0, stream>>>(features, augf, Wbf, XWs);

  // XCD-sliced SpMM, one phase per launch (per-XCD working set = 3.2MB slice)
  k_spmm_slice<<<SPMM_BLOCKS, 256, 0, stream>>>(row_ptr, ecol, eval,
                                                XWs, b1, O);
  k_spmm_slice<<<SPMM_BLOCKS, 256, 0, stream>>>(row_ptr, ecol, eval,
                                                XWs + (size_t)NPAIR * MPAD * SLICE_COLS,
                                                b1, O + (size_t)N_NODES * DH);

  // epilogue: S softmax + global partials
  k_post<<<POST_BLOCKS, 256, 0, stream>>>(O, Wt, bt, S, exptot, augtot,
                                          scal + 18, scal + 0);

  // graph stats on assignments
  k_edge<<<512, 256, 0, stream>>>(grow, gcol, gvals, S, scal + 2, scal + 1);

  // final scalar
  k_final<<<1, 256, 0, stream>>>(exptot, augtot, scal, (float*)d_out);
}

// Round 10
// 614.569 us; speedup vs baseline: 1.1718x; 1.0615x over previous
//
#include <hip/hip_runtime.h>
#include <math.h>

// Problem constants (fixed by reference)
#define N_NODES 50000
#define N_FEAT  500
#define DH      256
#define KC      16
#define NE      800000
#define KPAD    512     // N_FEAT padded to MFMA K multiple
#define MPAD    50048   // 391 * 128 (GEMM M tiles)
#define M2      (2 * MPAD)
#define SLICE_COLS 32   // D-slice per XCD: 50048*32*2B = 3.2MB fits 4MB L2
#define NPAIR   8       // 8 col-slices per matrix
#define SPMM_BLOCKS 2048
#define ROWS_PER_BLK 196  // ceil(50000/256)
#define POST_BLOCKS 2048

#define R16(X) X(0) X(1) X(2) X(3) X(4) X(5) X(6) X(7) \
               X(8) X(9) X(10) X(11) X(12) X(13) X(14) X(15)

typedef __attribute__((ext_vector_type(8))) short short8;
typedef __attribute__((ext_vector_type(4))) float f32x4;

__device__ __forceinline__ unsigned short f2bf(float f) {
  unsigned u = __float_as_uint(f);
  u += 0x7FFFu + ((u >> 16) & 1u);   // RNE
  return (unsigned short)(u >> 16);
}

__device__ __forceinline__ float bf2f(unsigned short u) {
  return __uint_as_float((unsigned)u << 16);
}

__device__ __forceinline__ float selu_f(float x) {
  return 1.0507009873554805f * (x > 0.f ? x : 1.6732632423543772f * expm1f(x));
}

__device__ __forceinline__ void gload16(const void* g, void* l) {
  __builtin_amdgcn_global_load_lds(
      (const __attribute__((address_space(1))) unsigned int*)g,
      (__attribute__((address_space(3))) unsigned int*)l, 16, 0, 0);
}

// ---- f32 -> bf16 with zero padding (used only for W1) ----
__global__ void k_cvt_pad(const float* __restrict__ in, unsigned short* __restrict__ out,
                          int rin, int cin, int rout, int cout) {
  const int cquads = cout >> 2;
  const long total = (long)rout * cquads;
  for (long idx = (long)blockIdx.x * blockDim.x + threadIdx.x; idx < total;
       idx += (long)gridDim.x * blockDim.x) {
    const int row = (int)(idx / cquads);
    const int c4  = (int)(idx - (long)row * cquads) * 4;
    float x = 0.f, y = 0.f, z = 0.f, w = 0.f;
    if (row < rin && c4 < cin) {
      const float4 v = *(const float4*)(in + (size_t)row * cin + c4);
      x = v.x; y = v.y; z = v.z; w = v.w;
    }
    ushort4 o; o.x = f2bf(x); o.y = f2bf(y); o.z = f2bf(z); o.w = f2bf(w);
    *(ushort4*)(out + (size_t)row * cout + c4) = o;
  }
}

// ---- Fused f32->bf16 GEMM: out[m][n] = sum_k A[m][k]*W[n][k]
//      A = features (rows [0,MPAD)) or aug ([MPAD,2*MPAD)), f32 [N][500]
//      W = Wbf bf16 [256][512]; tile 128x256, 512 threads, 8 waves of 64x64.
//      A-stage loads are BRANCHLESS (clamped addr + cndmask zero) and issued
//      BEFORE the B gloads, so 4 A-loads/lane are in flight before the first
//      ds_write waitcnt (R9 profile: MfmaUtil 7%, VALU 8% -> MLP-starved).
//      Output: slice-major XWs[pair][node][32]; C staged via As -> 16B stores. ----
__global__ __launch_bounds__(512, 2) void k_gemm_fused(
    const float* __restrict__ Af, const float* __restrict__ Aa,
    const unsigned short* __restrict__ Wbf, unsigned short* __restrict__ XWs) {
  __shared__ short As[128 * 64];
  __shared__ short Bs[256 * 64];
  const int t = threadIdx.x;
  const int lane = t & 63, wave = t >> 6;
  const int wr = (wave >> 2) * 64, wc = (wave & 3) * 64;
  const int bm = blockIdx.x * 128;
  const bool isaug = bm >= MPAD;
  const float* __restrict__ src = isaug ? Aa : Af;
  const int row0 = isaug ? bm - MPAD : bm;
  const int lr = lane & 15, lk = (lane >> 4) * 8;
  const int ar = t >> 3, ac = (t & 7) * 8;
  f32x4 acc[4][4] = {};
  for (int kb = 0; kb < KPAD; kb += 64) {
    // A loads first: branchless, all 4 in flight
    float4 ua[2][2];
#pragma unroll
    for (int h = 0; h < 2; ++h) {
      const int gr = row0 + ar + h * 64;
      const bool vr = gr < N_NODES;
      const float* arow = src + (size_t)(vr ? gr : 0) * N_FEAT;
      const int c = kb + ac;
      ua[h][0] = *(const float4*)(arow + min(c, N_FEAT - 4));
      ua[h][1] = *(const float4*)(arow + min(c + 4, N_FEAT - 4));
    }
    // B stage: 256x64 bf16 via global_load_lds (after A so A's waitcnt is cheap)
#pragma unroll
    for (int i = 0; i < 4; ++i) {
      const int chunk = i * 512 + t;
      const int rb = chunk >> 3, sub = (chunk & 7) * 8;
      gload16(Wbf + (size_t)rb * KPAD + kb + sub, (void*)(Bs + (size_t)chunk * 8));
    }
    // mask + pack + ds_write
#pragma unroll
    for (int h = 0; h < 2; ++h) {
      const int gr = row0 + ar + h * 64;
      const bool vr = gr < N_NODES;
      const int c = kb + ac;
      const bool ok0 = vr && (c < N_FEAT);
      const bool ok1 = vr && (c + 4 < N_FEAT);
      float4 u0 = ua[h][0], u1 = ua[h][1];
      u0.x = ok0 ? u0.x : 0.f; u0.y = ok0 ? u0.y : 0.f;
      u0.z = ok0 ? u0.z : 0.f; u0.w = ok0 ? u0.w : 0.f;
      u1.x = ok1 ? u1.x : 0.f; u1.y = ok1 ? u1.y : 0.f;
      u1.z = ok1 ? u1.z : 0.f; u1.w = ok1 ? u1.w : 0.f;
      short8 w;
      w[0] = (short)f2bf(u0.x); w[1] = (short)f2bf(u0.y);
      w[2] = (short)f2bf(u0.z); w[3] = (short)f2bf(u0.w);
      w[4] = (short)f2bf(u1.x); w[5] = (short)f2bf(u1.y);
      w[6] = (short)f2bf(u1.z); w[7] = (short)f2bf(u1.w);
      *(short8*)(As + (size_t)(ar + h * 64) * 64 + ac) = w;
    }
    __syncthreads();
#pragma unroll
    for (int kk = 0; kk < 64; kk += 32) {
      short8 af[4], bfr[4];
#pragma unroll
      for (int mi = 0; mi < 4; ++mi)
        af[mi] = *(const short8*)(As + (wr + mi * 16 + lr) * 64 + kk + lk);
#pragma unroll
      for (int n = 0; n < 4; ++n)
        bfr[n] = *(const short8*)(Bs + (wc + n * 16 + lr) * 64 + kk + lk);
#pragma unroll
      for (int mi = 0; mi < 4; ++mi)
#pragma unroll
        for (int n = 0; n < 4; ++n)
          acc[mi][n] = __builtin_amdgcn_mfma_f32_16x16x32_bf16(af[mi], bfr[n], acc[mi][n], 0, 0, 0);
    }
    __syncthreads();
  }
  // ---- coalesced C-write: 4 passes of 64 cols via As ----
  const int crow = (lane >> 4) * 4, ccol = lane & 15;
  const int phb8 = isaug ? NPAIR : 0;
  const int snode = t >> 2, ssub = t & 3;   // 128 nodes x 4 16B-chunks
#pragma unroll
  for (int cb = 0; cb < 4; ++cb) {
    if ((wave & 3) == cb) {   // the 2 waves owning cols [cb*64, cb*64+64)
#pragma unroll
      for (int mi = 0; mi < 4; ++mi)
#pragma unroll
        for (int n = 0; n < 4; ++n)
#pragma unroll
          for (int r = 0; r < 4; ++r)
            As[(wr + mi * 16 + crow + r) * 64 + n * 16 + ccol] =
                (short)f2bf(acc[mi][n][r]);
    }
    __syncthreads();
#pragma unroll
    for (int p2 = 0; p2 < 2; ++p2) {
      const int pair = phb8 + cb * 2 + p2;
      const short8 vv = *(const short8*)(As + snode * 64 + p2 * 32 + ssub * 8);
      *(short8*)(XWs + ((size_t)pair * MPAD + row0 + snode) * SLICE_COLS + ssub * 8) = vv;
    }
    __syncthreads();
  }
}

// ---- CSR build ----
__global__ void k_count(const int* __restrict__ row, int* __restrict__ counts) {
  const int e = blockIdx.x * blockDim.x + threadIdx.x;
  if (e < NE) atomicAdd(&counts[row[e]], 1);
}

__global__ __launch_bounds__(1024) void k_scan(const int* __restrict__ counts,
                                               int* __restrict__ row_ptr, int* __restrict__ cursor) {
  __shared__ int part[1024];
  const int t = threadIdx.x;
  const int per = (N_NODES + 1023) / 1024;
  const int base = t * per;
  int s = 0;
  for (int i = 0; i < per; ++i) { const int j = base + i; if (j < N_NODES) s += counts[j]; }
  part[t] = s;
  __syncthreads();
  for (int off = 1; off < 1024; off <<= 1) {
    const int v = (t >= off) ? part[t - off] : 0;
    __syncthreads();
    part[t] += v;
    __syncthreads();
  }
  int run = (t == 0) ? 0 : part[t - 1];
  for (int i = 0; i < per; ++i) {
    const int j = base + i;
    if (j < N_NODES) { row_ptr[j] = run; cursor[j] = run; run += counts[j]; }
  }
  if (t == 1023) row_ptr[N_NODES] = part[1023];
}

__global__ void k_scatter(const int* __restrict__ row, const int* __restrict__ col,
                          const float* __restrict__ gnv, int* __restrict__ cursor,
                          int* __restrict__ ecol, float* __restrict__ eval) {
  const int e = blockIdx.x * blockDim.x + threadIdx.x;
  if (e < NE) {
    const int p = atomicAdd(&cursor[row[e]], 1);
    ecol[p] = col[e];
    eval[p] = gnv[e];
  }
}

// ---- XCD-sliced SpMM + bias + selu -> O (bf16). One phase per launch. ----
__global__ __launch_bounds__(256, 4) void k_spmm_slice(
    const int* __restrict__ row_ptr, const int* __restrict__ ecol, const float* __restrict__ eval,
    const unsigned short* __restrict__ XWp,  // phase base: XWs + ph*8*MPAD*32
    const float* __restrict__ b1,
    unsigned short* __restrict__ Ob) {       // phase base: O + ph*N*DH
  const int slice = blockIdx.x & 7;
  const int rblk  = blockIdx.x >> 3;
  const int r0 = rblk * ROWS_PER_BLK;
  const int r1 = min(r0 + ROWS_PER_BLK, N_NODES);
  const int wave = threadIdx.x >> 6, lane = threadIdx.x & 63;
  const int g = lane >> 2, sub = lane & 3;
  const int scol = slice * SLICE_COLS + sub * 8;

  const float4 b0 = *(const float4*)(b1 + scol);
  const float4 b4 = *(const float4*)(b1 + scol + 4);
  const unsigned short* __restrict__ Xb =
      XWp + (size_t)slice * MPAD * SLICE_COLS + sub * 8;

  for (int rb = r0; rb < r1; rb += 64) {
    const int row = rb + wave * 16 + g;
    if (row >= r1) continue;
    const int s = row_ptr[row], e = row_ptr[row + 1];
    float acc[8] = {0.f, 0.f, 0.f, 0.f, 0.f, 0.f, 0.f, 0.f};
    int p = s;
    for (; p + 1 < e; p += 2) {
      const int   c0 = ecol[p],  c1 = ecol[p + 1];
      const float v0 = eval[p],  v1 = eval[p + 1];
      const short8 x0 = *(const short8*)(Xb + (size_t)c0 * SLICE_COLS);
      const short8 x1 = *(const short8*)(Xb + (size_t)c1 * SLICE_COLS);
#pragma unroll
      for (int u = 0; u < 8; ++u) {
        acc[u] += v0 * bf2f((unsigned short)x0[u]);
        acc[u] += v1 * bf2f((unsigned short)x1[u]);
      }
    }
    if (p < e) {
      const int   c0 = ecol[p];
      const float v0 = eval[p];
      const short8 x0 = *(const short8*)(Xb + (size_t)c0 * SLICE_COLS);
#pragma unroll
      for (int u = 0; u < 8; ++u) acc[u] += v0 * bf2f((unsigned short)x0[u]);
    }
    short8 o;
    o[0] = (short)f2bf(selu_f(acc[0] + b0.x));
    o[1] = (short)f2bf(selu_f(acc[1] + b0.y));
    o[2] = (short)f2bf(selu_f(acc[2] + b0.z));
    o[3] = (short)f2bf(selu_f(acc[3] + b0.w));
    o[4] = (short)f2bf(selu_f(acc[4] + b4.x));
    o[5] = (short)f2bf(selu_f(acc[5] + b4.y));
    o[6] = (short)f2bf(selu_f(acc[6] + b4.z));
    o[7] = (short)f2bf(selu_f(acc[7] + b4.w));
    *(short8*)(Ob + (size_t)row * DH + scol) = o;
  }
}

// ---- Epilogue over O: S softmax, exp-colsums, aug-colsums, dot, cluster sizes.
//      lg[] array replaced by EXPLICIT SCALARS l0..l15 (R9: the array went to
//      scratch -> 143MB spill writes, 214us). launch_bounds(256,2) for headroom. ----
__global__ __launch_bounds__(256, 2) void k_post(
    const unsigned short* __restrict__ O, const float* __restrict__ Wt,
    const float* __restrict__ bt, float* __restrict__ S,
    float* __restrict__ exptot, float* __restrict__ augtot,
    float* __restrict__ csg, float* __restrict__ dotAG) {
  __shared__ float expacc[DH];
  __shared__ float augacc[DH];
  __shared__ float csacc[KC];
  __shared__ float dacc;
  expacc[threadIdx.x] = 0.f;
  augacc[threadIdx.x] = 0.f;
  if (threadIdx.x < KC) csacc[threadIdx.x] = 0.f;
  if (threadIdx.x == 0) dacc = 0.f;
  __syncthreads();

  const int wave = threadIdx.x >> 6, lane = threadIdx.x & 63;
  const int c0 = lane * 4;
  const unsigned short* Of = O;
  const unsigned short* Oa = O + (size_t)N_NODES * DH;

  float lexp0 = 0.f, lexp1 = 0.f, lexp2 = 0.f, lexp3 = 0.f;
  float laug0 = 0.f, laug1 = 0.f, laug2 = 0.f, laug3 = 0.f;
  float ldot = 0.f, lcs = 0.f;
#define LDBT(K) const float bt_##K = bt[K];
  R16(LDBT)
#undef LDBT

  for (int i = blockIdx.x * 4 + wave; i < N_NODES; i += POST_BLOCKS * 4) {
    const ushort4 fu = *(const ushort4*)(Of + (size_t)i * DH + c0);
    const ushort4 au = *(const ushort4*)(Oa + (size_t)i * DH + c0);
    const float of0 = bf2f(fu.x), of1 = bf2f(fu.y), of2 = bf2f(fu.z), of3 = bf2f(fu.w);
    const float oa0 = bf2f(au.x), oa1 = bf2f(au.y), oa2 = bf2f(au.z), oa3 = bf2f(au.w);
    lexp0 += expf(of0); lexp1 += expf(of1); lexp2 += expf(of2); lexp3 += expf(of3);
    laug0 += oa0; laug1 += oa1; laug2 += oa2; laug3 += oa3;
    ldot += of0 * oa0 + of1 * oa1 + of2 * oa2 + of3 * oa3;

#define DOT(K) float l##K; { const float4 w = *(const float4*)(Wt + K * DH + c0); \
                             l##K = of0 * w.x + of1 * w.y + of2 * w.z + of3 * w.w; }
    R16(DOT)
#undef DOT
#pragma unroll
    for (int off = 32; off; off >>= 1) {
#define SHF(K) l##K += __shfl_xor(l##K, off);
      R16(SHF)
#undef SHF
    }
#define BIAS(K) l##K += bt_##K;
    R16(BIAS)
#undef BIAS
    float mx = l0;
#define MX(K) mx = fmaxf(mx, l##K);
    R16(MX)
#undef MX
    float se = 0.f;
#define EXPK(K) l##K = expf(l##K - mx); se += l##K;
    R16(EXPK)
#undef EXPK
    const float inv = 1.f / se;
    float myv = 0.f;
#define SEL(K) if (lane == K) myv = l##K;
    R16(SEL)
#undef SEL
    if (lane < KC) {
      const float sv = myv * inv;
      S[(size_t)i * KC + lane] = sv;
      lcs += sv;
    }
  }

#pragma unroll
  for (int off = 32; off; off >>= 1) ldot += __shfl_xor(ldot, off);
  if (lane == 0) atomicAdd(&dacc, ldot);
  atomicAdd(&expacc[c0 + 0], lexp0);
  atomicAdd(&expacc[c0 + 1], lexp1);
  atomicAdd(&expacc[c0 + 2], lexp2);
  atomicAdd(&expacc[c0 + 3], lexp3);
  atomicAdd(&augacc[c0 + 0], laug0);
  atomicAdd(&augacc[c0 + 1], laug1);
  atomicAdd(&augacc[c0 + 2], laug2);
  atomicAdd(&augacc[c0 + 3], laug3);
  if (lane < KC) atomicAdd(&csacc[lane], lcs);
  __syncthreads();
  atomicAdd(&exptot[threadIdx.x], expacc[threadIdx.x]);
  atomicAdd(&augtot[threadIdx.x], augacc[threadIdx.x]);
  if (threadIdx.x < KC) atomicAdd(&csg[threadIdx.x], csacc[threadIdx.x]);
  if (threadIdx.x == 0) atomicAdd(dotAG, dacc);
}

// ---- edge stats: tp = sum_e v*dot16(S[row],S[col]); nl[k] = sum_e v*S[col,k] ----
__global__ __launch_bounds__(256) void k_edge(const int* __restrict__ grow, const int* __restrict__ gcol,
                                              const float* __restrict__ gvals, const float* __restrict__ S,
                                              float* __restrict__ nl, float* __restrict__ tp) {
  float ltp = 0.f;
  float lnl[KC];
#pragma unroll
  for (int k = 0; k < KC; ++k) lnl[k] = 0.f;
  for (long e = (long)blockIdx.x * 256 + threadIdx.x; e < NE; e += (long)gridDim.x * 256) {
    const int r = grow[e], c = gcol[e];
    const float v = gvals[e];
    const float4* sr = (const float4*)(S + (size_t)r * KC);
    const float4* sc = (const float4*)(S + (size_t)c * KC);
    const float4 a0 = sr[0], a1 = sr[1], a2 = sr[2], a3 = sr[3];
    const float4 b0 = sc[0], b1v = sc[1], b2 = sc[2], b3 = sc[3];
    const float dot = a0.x * b0.x + a0.y * b0.y + a0.z * b0.z + a0.w * b0.w
                    + a1.x * b1v.x + a1.y * b1v.y + a1.z * b1v.z + a1.w * b1v.w
                    + a2.x * b2.x + a2.y * b2.y + a2.z * b2.z + a2.w * b2.w
                    + a3.x * b3.x + a3.y * b3.y + a3.z * b3.z + a3.w * b3.w;
    ltp += v * dot;
    lnl[0] += v * b0.x;  lnl[1] += v * b0.y;  lnl[2] += v * b0.z;  lnl[3] += v * b0.w;
    lnl[4] += v * b1v.x; lnl[5] += v * b1v.y; lnl[6] += v * b1v.z; lnl[7] += v * b1v.w;
    lnl[8] += v * b2.x;  lnl[9] += v * b2.y;  lnl[10] += v * b2.z; lnl[11] += v * b2.w;
    lnl[12] += v * b3.x; lnl[13] += v * b3.y; lnl[14] += v * b3.z; lnl[15] += v * b3.w;
  }
#pragma unroll
  for (int off = 32; off; off >>= 1) {
    ltp += __shfl_xor(ltp, off);
#pragma unroll
    for (int k = 0; k < KC; ++k) lnl[k] += __shfl_xor(lnl[k], off);
  }
  __shared__ float wred[4][KC + 1];
  const int wave = threadIdx.x >> 6, lane = threadIdx.x & 63;
  if (lane == 0) {
    wred[wave][0] = ltp;
#pragma unroll
    for (int k = 0; k < KC; ++k) wred[wave][1 + k] = lnl[k];
  }
  __syncthreads();
  if (threadIdx.x < KC + 1) {
    const float s = wred[0][threadIdx.x] + wred[1][threadIdx.x] + wred[2][threadIdx.x] + wred[3][threadIdx.x];
    if (threadIdx.x == 0) atomicAdd(tp, s);
    else atomicAdd(&nl[threadIdx.x - 1], s);
  }
}

// ---- final scalar assembly ----
// scal layout: [0]=dotAG, [1]=tp, [2..17]=nl, [18..33]=cs
__global__ void k_final(const float* __restrict__ exptot, const float* __restrict__ augtot,
                        const float* __restrict__ scal, float* __restrict__ out) {
  const int d = threadIdx.x;
  const float L = logf(exptot[d]);
  const float sa = augtot[d];
  __shared__ float red[DH];
  red[d] = L * sa;
  __syncthreads();
  for (int off = 128; off; off >>= 1) {
    if (d < off) red[d] += red[d + off];
    __syncthreads();
  }
  if (d == 0) {
    const float sumLA = red[0];
    const float dotAG = scal[0];
    const float tp = scal[1];
    float nl2 = 0.f, cs2 = 0.f;
#pragma unroll
    for (int k = 0; k < KC; ++k) {
      nl2 += scal[2 + k] * scal[2 + k];
      cs2 += scal[18 + k] * scal[18 + k];
    }
    const float fE = (float)NE;
    const float con = -(dotAG - sumLA) / (float)DH;
    const float trn = nl2 / (2.f * fE);
    const float spectral = -(tp - trn) / (2.f * fE);
    const float cluster = (sqrtf(cs2) / (float)N_NODES * 4.f - 1.f);
    out[0] = spectral + cluster + 0.5f * con;
  }
}

extern "C" void kernel_launch(void* const* d_in, const int* in_sizes, int n_in,
                              void* d_out, int out_size, void* d_ws, size_t ws_size,
                              hipStream_t stream) {
  const float* features = (const float*)d_in[0];
  const float* augf     = (const float*)d_in[1];
  const int*   grow     = (const int*)d_in[2];
  const int*   gcol     = (const int*)d_in[3];
  const float* gvals    = (const float*)d_in[4];
  const float* gnv      = (const float*)d_in[5];
  const float* W1       = (const float*)d_in[8];
  const float* b1       = (const float*)d_in[9];
  const float* Wt       = (const float*)d_in[10];
  const float* bt       = (const float*)d_in[11];

  char* ws = (char*)d_ws;
  size_t off = 0;
  auto alloc = [&](size_t bytes) -> void* {
    void* p = ws + off;
    off = (off + bytes + 255) & ~(size_t)255;
    return p;
  };
  unsigned short* Wbf  = (unsigned short*)alloc((size_t)DH * KPAD * 2);
  unsigned short* XWs  = (unsigned short*)alloc((size_t)16 * MPAD * SLICE_COLS * 2);
  unsigned short* O    = (unsigned short*)alloc((size_t)2 * N_NODES * DH * 2);
  float* S       = (float*)alloc((size_t)N_NODES * KC * 4);
  int*   ecol    = (int*)alloc((size_t)NE * 4);
  float* eval    = (float*)alloc((size_t)NE * 4);
  int*   row_ptr = (int*)alloc((size_t)(N_NODES + 1) * 4);
  int*   cursor  = (int*)alloc((size_t)N_NODES * 4);
  int*   counts  = (int*)alloc((size_t)N_NODES * 4);
  float* exptot  = (float*)alloc((size_t)DH * 4);   // contiguous zero region:
  float* augtot  = (float*)alloc((size_t)DH * 4);   //   exptot | augtot | scal
  float* scal    = (float*)alloc(64 * 4);
  if (off > ws_size) return;  // workspace too small: fail loudly, no OOB

  hipMemsetAsync(counts, 0, (size_t)N_NODES * 4, stream);
  hipMemsetAsync(exptot, 0, (size_t)DH * 4 * 2 + 64 * 4, stream);

  // W1 -> bf16 (tiny)
  k_cvt_pad<<<128, 256, 0, stream>>>(W1, Wbf, DH, N_FEAT, DH, KPAD);

  // CSR build
  k_count<<<(NE + 255) / 256, 256, 0, stream>>>(grow, counts);
  k_scan<<<1, 1024, 0, stream>>>(counts, row_ptr, cursor);
  k_scatter<<<(NE + 255) / 256, 256, 0, stream>>>(grow, gcol, gnv, cursor, ecol, eval);

  // fused-conversion GEMM over both matrices -> slice-major XWs (coalesced C)
  k_gemm_fused<<<M2 / 128, 512, 0, stream>>>(features, augf, Wbf, XWs);

  // XCD-sliced SpMM, one phase per launch (per-XCD working set = 3.2MB slice)
  k_spmm_slice<<<SPMM_BLOCKS, 256, 0, stream>>>(row_ptr, ecol, eval,
                                                XWs, b1, O);
  k_spmm_slice<<<SPMM_BLOCKS, 256, 0, stream>>>(row_ptr, ecol, eval,
                                                XWs + (size_t)NPAIR * MPAD * SLICE_COLS,
                                                b1, O + (size_t)N_NODES * DH);

  // epilogue: S softmax + global partials
  k_post<<<POST_BLOCKS, 256, 0, stream>>>(O, Wt, bt, S, exptot, augtot,
                                          scal + 18, scal + 0);

  // graph stats on assignments
  k_edge<<<512, 256, 0, stream>>>(grow, gcol, gvals, S, scal + 2, scal + 1);

  // final scalar
  k_final<<<1, 256, 0, stream>>>(exptot, augtot, scal, (float*)d_out);
}

// Round 11
// 599.017 us; speedup vs baseline: 1.2022x; 1.0260x over previous
//
#include <hip/hip_runtime.h>
#include <math.h>

// Problem constants (fixed by reference)
#define N_NODES 50000
#define N_FEAT  500
#define DH      256
#define KC      16
#define NE      800000
#define KPAD    512     // N_FEAT padded to MFMA K multiple
#define MPAD    50048   // 391 * 128 (GEMM M tiles)
#define M2      (2 * MPAD)
#define SLICE_COLS 32   // D-slice per XCD: 50048*32*2B = 3.2MB fits 4MB L2
#define NPAIR   8       // 8 col-slices per matrix
#define SPMM_BLOCKS 2048
#define ROWS_PER_BLK 196  // ceil(50000/256)
#define POST_BLOCKS 2048

#define R16(X) X(0) X(1) X(2) X(3) X(4) X(5) X(6) X(7) \
               X(8) X(9) X(10) X(11) X(12) X(13) X(14) X(15)

typedef __attribute__((ext_vector_type(8))) short short8;
typedef __attribute__((ext_vector_type(4))) float f32x4;

__device__ __forceinline__ unsigned short f2bf(float f) {
  unsigned u = __float_as_uint(f);
  u += 0x7FFFu + ((u >> 16) & 1u);   // RNE
  return (unsigned short)(u >> 16);
}

__device__ __forceinline__ float bf2f(unsigned short u) {
  return __uint_as_float((unsigned)u << 16);
}

__device__ __forceinline__ float selu_f(float x) {
  return 1.0507009873554805f * (x > 0.f ? x : 1.6732632423543772f * expm1f(x));
}

__device__ __forceinline__ void gload16(const void* g, void* l) {
  __builtin_amdgcn_global_load_lds(
      (const __attribute__((address_space(1))) unsigned int*)g,
      (__attribute__((address_space(3))) unsigned int*)l, 16, 0, 0);
}

// ---- W1 f32 -> bf16, zero-padded AND pre-swizzled so that the GEMM's linear
//      global_load_lds lands each 16B chunk at its XOR-swizzled LDS slot:
//      Wbf[row][kb + cc*8 ..] = W1[row][kb + (cc^(row&7))*8 ..]  (rule #21 /
//      m173 pattern: swizzle the SOURCE, keep LDS dest linear). ----
__global__ void k_cvt_w1(const float* __restrict__ in, unsigned short* __restrict__ out) {
  const int idx = blockIdx.x * 256 + threadIdx.x;   // one 16B chunk each
  if (idx >= DH * (KPAD / 8)) return;
  const int row = idx >> 6;          // 0..255
  const int cc  = idx & 63;          // out chunk within row
  const int scc = (cc & ~7) | ((cc & 7) ^ (row & 7));   // source chunk
  const int c0 = scc * 8;
  short8 w;
#pragma unroll
  for (int j = 0; j < 8; ++j) {
    const int col = c0 + j;
    w[j] = (col < N_FEAT) ? (short)f2bf(in[(size_t)row * N_FEAT + col]) : (short)0;
  }
  *(short8*)(out + (size_t)row * KPAD + cc * 8) = w;
}

// ---- Fused f32->bf16 GEMM: out[m][n] = sum_k A[m][k]*W[n][k]
//      Tile 128x256, 512 threads, 8 waves of 64x64.
//      R10 profile: 10.6M LDS bank conflicts (128B row stride -> 16-way on
//      every fragment read), MfmaUtil 7.5%. Fix: T2 XOR-swizzle
//      (chunk ^= row&7) on As write/read, C-stage write/read; Bs gets the
//      same swizzle via the pre-permuted Wbf + linear global_load_lds. ----
__global__ __launch_bounds__(512, 2) void k_gemm_fused(
    const float* __restrict__ Af, const float* __restrict__ Aa,
    const unsigned short* __restrict__ Wbf, unsigned short* __restrict__ XWs) {
  __shared__ short As[128 * 64];
  __shared__ short Bs[256 * 64];
  const int t = threadIdx.x;
  const int lane = t & 63, wave = t >> 6;
  const int wr = (wave >> 2) * 64, wc = (wave & 3) * 64;
  const int bm = blockIdx.x * 128;
  const bool isaug = bm >= MPAD;
  const float* __restrict__ src = isaug ? Aa : Af;
  const int row0 = isaug ? bm - MPAD : bm;
  const int lr = lane & 15, lk = (lane >> 4) * 8;
  const int rsw = (lr & 7) * 8;            // read-side swizzle (const per lane)
  const int ar = t >> 3, ac = (t & 7) * 8;
  const int aw = ac ^ ((ar & 7) * 8);      // A-stage write swizzle
  f32x4 acc[4][4] = {};
  for (int kb = 0; kb < KPAD; kb += 64) {
    // A loads first: branchless, all 4 in flight
    float4 ua[2][2];
#pragma unroll
    for (int h = 0; h < 2; ++h) {
      const int gr = row0 + ar + h * 64;
      const bool vr = gr < N_NODES;
      const float* arow = src + (size_t)(vr ? gr : 0) * N_FEAT;
      const int c = kb + ac;
      ua[h][0] = *(const float4*)(arow + min(c, N_FEAT - 4));
      ua[h][1] = *(const float4*)(arow + min(c + 4, N_FEAT - 4));
    }
    // B stage: 256x64 bf16 via global_load_lds (source pre-swizzled)
#pragma unroll
    for (int i = 0; i < 4; ++i) {
      const int chunk = i * 512 + t;
      const int rb = chunk >> 3, sub = (chunk & 7) * 8;
      gload16(Wbf + (size_t)rb * KPAD + kb + sub, (void*)(Bs + (size_t)chunk * 8));
    }
    // mask + pack + swizzled ds_write
#pragma unroll
    for (int h = 0; h < 2; ++h) {
      const int gr = row0 + ar + h * 64;
      const bool vr = gr < N_NODES;
      const int c = kb + ac;
      const bool ok0 = vr && (c < N_FEAT);
      const bool ok1 = vr && (c + 4 < N_FEAT);
      float4 u0 = ua[h][0], u1 = ua[h][1];
      u0.x = ok0 ? u0.x : 0.f; u0.y = ok0 ? u0.y : 0.f;
      u0.z = ok0 ? u0.z : 0.f; u0.w = ok0 ? u0.w : 0.f;
      u1.x = ok1 ? u1.x : 0.f; u1.y = ok1 ? u1.y : 0.f;
      u1.z = ok1 ? u1.z : 0.f; u1.w = ok1 ? u1.w : 0.f;
      short8 w;
      w[0] = (short)f2bf(u0.x); w[1] = (short)f2bf(u0.y);
      w[2] = (short)f2bf(u0.z); w[3] = (short)f2bf(u0.w);
      w[4] = (short)f2bf(u1.x); w[5] = (short)f2bf(u1.y);
      w[6] = (short)f2bf(u1.z); w[7] = (short)f2bf(u1.w);
      *(short8*)(As + (size_t)(ar + h * 64) * 64 + aw) = w;
    }
    __syncthreads();
#pragma unroll
    for (int kk = 0; kk < 64; kk += 32) {
      short8 af[4], bfr[4];
#pragma unroll
      for (int mi = 0; mi < 4; ++mi)
        af[mi] = *(const short8*)(As + (wr + mi * 16 + lr) * 64 + ((kk + lk) ^ rsw));
#pragma unroll
      for (int n = 0; n < 4; ++n)
        bfr[n] = *(const short8*)(Bs + (wc + n * 16 + lr) * 64 + ((kk + lk) ^ rsw));
#pragma unroll
      for (int mi = 0; mi < 4; ++mi)
#pragma unroll
        for (int n = 0; n < 4; ++n)
          acc[mi][n] = __builtin_amdgcn_mfma_f32_16x16x32_bf16(af[mi], bfr[n], acc[mi][n], 0, 0, 0);
    }
    __syncthreads();
  }
  // ---- coalesced C-write: 4 passes of 64 cols via As (swizzled staging) ----
  const int crow = (lane >> 4) * 4, ccol = lane & 15;
  const int phb8 = isaug ? NPAIR : 0;
  const int snode = t >> 2, ssub = t & 3;   // 128 nodes x 4 16B-chunks
  const int csw = (snode & 7) * 8;          // C-stage read swizzle
#pragma unroll
  for (int cb = 0; cb < 4; ++cb) {
    if ((wave & 3) == cb) {   // the 2 waves owning cols [cb*64, cb*64+64)
#pragma unroll
      for (int mi = 0; mi < 4; ++mi)
#pragma unroll
        for (int n = 0; n < 4; ++n)
#pragma unroll
          for (int r = 0; r < 4; ++r)
            As[(wr + mi * 16 + crow + r) * 64 +
               ((n * 16 + ccol) ^ (((crow + r) & 7) * 8))] =
                (short)f2bf(acc[mi][n][r]);
    }
    __syncthreads();
#pragma unroll
    for (int p2 = 0; p2 < 2; ++p2) {
      const int pair = phb8 + cb * 2 + p2;
      const short8 vv = *(const short8*)(As + snode * 64 + ((p2 * 32 + ssub * 8) ^ csw));
      *(short8*)(XWs + ((size_t)pair * MPAD + row0 + snode) * SLICE_COLS + ssub * 8) = vv;
    }
    __syncthreads();
  }
}

// ---- CSR build ----
__global__ void k_count(const int* __restrict__ row, int* __restrict__ counts) {
  const int e = blockIdx.x * blockDim.x + threadIdx.x;
  if (e < NE) atomicAdd(&counts[row[e]], 1);
}

__global__ __launch_bounds__(1024) void k_scan(const int* __restrict__ counts,
                                               int* __restrict__ row_ptr, int* __restrict__ cursor) {
  __shared__ int part[1024];
  const int t = threadIdx.x;
  const int per = (N_NODES + 1023) / 1024;
  const int base = t * per;
  int s = 0;
  for (int i = 0; i < per; ++i) { const int j = base + i; if (j < N_NODES) s += counts[j]; }
  part[t] = s;
  __syncthreads();
  for (int off = 1; off < 1024; off <<= 1) {
    const int v = (t >= off) ? part[t - off] : 0;
    __syncthreads();
    part[t] += v;
    __syncthreads();
  }
  int run = (t == 0) ? 0 : part[t - 1];
  for (int i = 0; i < per; ++i) {
    const int j = base + i;
    if (j < N_NODES) { row_ptr[j] = run; cursor[j] = run; run += counts[j]; }
  }
  if (t == 1023) row_ptr[N_NODES] = part[1023];
}

__global__ void k_scatter(const int* __restrict__ row, const int* __restrict__ col,
                          const float* __restrict__ gnv, int* __restrict__ cursor,
                          int* __restrict__ ecol, float* __restrict__ eval) {
  const int e = blockIdx.x * blockDim.x + threadIdx.x;
  if (e < NE) {
    const int p = atomicAdd(&cursor[row[e]], 1);
    ecol[p] = col[e];
    eval[p] = gnv[e];
  }
}

// ---- XCD-sliced SpMM + bias + selu -> O (bf16). One phase per launch. ----
__global__ __launch_bounds__(256, 4) void k_spmm_slice(
    const int* __restrict__ row_ptr, const int* __restrict__ ecol, const float* __restrict__ eval,
    const unsigned short* __restrict__ XWp,  // phase base: XWs + ph*8*MPAD*32
    const float* __restrict__ b1,
    unsigned short* __restrict__ Ob) {       // phase base: O + ph*N*DH
  const int slice = blockIdx.x & 7;
  const int rblk  = blockIdx.x >> 3;
  const int r0 = rblk * ROWS_PER_BLK;
  const int r1 = min(r0 + ROWS_PER_BLK, N_NODES);
  const int wave = threadIdx.x >> 6, lane = threadIdx.x & 63;
  const int g = lane >> 2, sub = lane & 3;
  const int scol = slice * SLICE_COLS + sub * 8;

  const float4 b0 = *(const float4*)(b1 + scol);
  const float4 b4 = *(const float4*)(b1 + scol + 4);
  const unsigned short* __restrict__ Xb =
      XWp + (size_t)slice * MPAD * SLICE_COLS + sub * 8;

  for (int rb = r0; rb < r1; rb += 64) {
    const int row = rb + wave * 16 + g;
    if (row >= r1) continue;
    const int s = row_ptr[row], e = row_ptr[row + 1];
    float acc[8] = {0.f, 0.f, 0.f, 0.f, 0.f, 0.f, 0.f, 0.f};
    int p = s;
    for (; p + 1 < e; p += 2) {
      const int   c0 = ecol[p],  c1 = ecol[p + 1];
      const float v0 = eval[p],  v1 = eval[p + 1];
      const short8 x0 = *(const short8*)(Xb + (size_t)c0 * SLICE_COLS);
      const short8 x1 = *(const short8*)(Xb + (size_t)c1 * SLICE_COLS);
#pragma unroll
      for (int u = 0; u < 8; ++u) {
        acc[u] += v0 * bf2f((unsigned short)x0[u]);
        acc[u] += v1 * bf2f((unsigned short)x1[u]);
      }
    }
    if (p < e) {
      const int   c0 = ecol[p];
      const float v0 = eval[p];
      const short8 x0 = *(const short8*)(Xb + (size_t)c0 * SLICE_COLS);
#pragma unroll
      for (int u = 0; u < 8; ++u) acc[u] += v0 * bf2f((unsigned short)x0[u]);
    }
    short8 o;
    o[0] = (short)f2bf(selu_f(acc[0] + b0.x));
    o[1] = (short)f2bf(selu_f(acc[1] + b0.y));
    o[2] = (short)f2bf(selu_f(acc[2] + b0.z));
    o[3] = (short)f2bf(selu_f(acc[3] + b0.w));
    o[4] = (short)f2bf(selu_f(acc[4] + b4.x));
    o[5] = (short)f2bf(selu_f(acc[5] + b4.y));
    o[6] = (short)f2bf(selu_f(acc[6] + b4.z));
    o[7] = (short)f2bf(selu_f(acc[7] + b4.w));
    *(short8*)(Ob + (size_t)row * DH + scol) = o;
  }
}

// ---- Epilogue over O: S softmax, exp-colsums, aug-colsums, dot, cluster sizes.
//      Explicit scalars l0..l15 (R9: array indexing spilled to scratch). ----
__global__ __launch_bounds__(256, 2) void k_post(
    const unsigned short* __restrict__ O, const float* __restrict__ Wt,
    const float* __restrict__ bt, float* __restrict__ S,
    float* __restrict__ exptot, float* __restrict__ augtot,
    float* __restrict__ csg, float* __restrict__ dotAG) {
  __shared__ float expacc[DH];
  __shared__ float augacc[DH];
  __shared__ float csacc[KC];
  __shared__ float dacc;
  expacc[threadIdx.x] = 0.f;
  augacc[threadIdx.x] = 0.f;
  if (threadIdx.x < KC) csacc[threadIdx.x] = 0.f;
  if (threadIdx.x == 0) dacc = 0.f;
  __syncthreads();

  const int wave = threadIdx.x >> 6, lane = threadIdx.x & 63;
  const int c0 = lane * 4;
  const unsigned short* Of = O;
  const unsigned short* Oa = O + (size_t)N_NODES * DH;

  float lexp0 = 0.f, lexp1 = 0.f, lexp2 = 0.f, lexp3 = 0.f;
  float laug0 = 0.f, laug1 = 0.f, laug2 = 0.f, laug3 = 0.f;
  float ldot = 0.f, lcs = 0.f;
#define LDBT(K) const float bt_##K = bt[K];
  R16(LDBT)
#undef LDBT

  for (int i = blockIdx.x * 4 + wave; i < N_NODES; i += POST_BLOCKS * 4) {
    const ushort4 fu = *(const ushort4*)(Of + (size_t)i * DH + c0);
    const ushort4 au = *(const ushort4*)(Oa + (size_t)i * DH + c0);
    const float of0 = bf2f(fu.x), of1 = bf2f(fu.y), of2 = bf2f(fu.z), of3 = bf2f(fu.w);
    const float oa0 = bf2f(au.x), oa1 = bf2f(au.y), oa2 = bf2f(au.z), oa3 = bf2f(au.w);
    lexp0 += expf(of0); lexp1 += expf(of1); lexp2 += expf(of2); lexp3 += expf(of3);
    laug0 += oa0; laug1 += oa1; laug2 += oa2; laug3 += oa3;
    ldot += of0 * oa0 + of1 * oa1 + of2 * oa2 + of3 * oa3;

#define DOT(K) float l##K; { const float4 w = *(const float4*)(Wt + K * DH + c0); \
                             l##K = of0 * w.x + of1 * w.y + of2 * w.z + of3 * w.w; }
    R16(DOT)
#undef DOT
#pragma unroll
    for (int off = 32; off; off >>= 1) {
#define SHF(K) l##K += __shfl_xor(l##K, off);
      R16(SHF)
#undef SHF
    }
#define BIAS(K) l##K += bt_##K;
    R16(BIAS)
#undef BIAS
    float mx = l0;
#define MX(K) mx = fmaxf(mx, l##K);
    R16(MX)
#undef MX
    float se = 0.f;
#define EXPK(K) l##K = expf(l##K - mx); se += l##K;
    R16(EXPK)
#undef EXPK
    const float inv = 1.f / se;
    float myv = 0.f;
#define SEL(K) if (lane == K) myv = l##K;
    R16(SEL)
#undef SEL
    if (lane < KC) {
      const float sv = myv * inv;
      S[(size_t)i * KC + lane] = sv;
      lcs += sv;
    }
  }

#pragma unroll
  for (int off = 32; off; off >>= 1) ldot += __shfl_xor(ldot, off);
  if (lane == 0) atomicAdd(&dacc, ldot);
  atomicAdd(&expacc[c0 + 0], lexp0);
  atomicAdd(&expacc[c0 + 1], lexp1);
  atomicAdd(&expacc[c0 + 2], lexp2);
  atomicAdd(&expacc[c0 + 3], lexp3);
  atomicAdd(&augacc[c0 + 0], laug0);
  atomicAdd(&augacc[c0 + 1], laug1);
  atomicAdd(&augacc[c0 + 2], laug2);
  atomicAdd(&augacc[c0 + 3], laug3);
  if (lane < KC) atomicAdd(&csacc[lane], lcs);
  __syncthreads();
  atomicAdd(&exptot[threadIdx.x], expacc[threadIdx.x]);
  atomicAdd(&augtot[threadIdx.x], augacc[threadIdx.x]);
  if (threadIdx.x < KC) atomicAdd(&csg[threadIdx.x], csacc[threadIdx.x]);
  if (threadIdx.x == 0) atomicAdd(dotAG, dacc);
}

// ---- edge stats: tp = sum_e v*dot16(S[row],S[col]); nl[k] = sum_e v*S[col,k] ----
__global__ __launch_bounds__(256) void k_edge(const int* __restrict__ grow, const int* __restrict__ gcol,
                                              const float* __restrict__ gvals, const float* __restrict__ S,
                                              float* __restrict__ nl, float* __restrict__ tp) {
  float ltp = 0.f;
  float lnl[KC];
#pragma unroll
  for (int k = 0; k < KC; ++k) lnl[k] = 0.f;
  for (long e = (long)blockIdx.x * 256 + threadIdx.x; e < NE; e += (long)gridDim.x * 256) {
    const int r = grow[e], c = gcol[e];
    const float v = gvals[e];
    const float4* sr = (const float4*)(S + (size_t)r * KC);
    const float4* sc = (const float4*)(S + (size_t)c * KC);
    const float4 a0 = sr[0], a1 = sr[1], a2 = sr[2], a3 = sr[3];
    const float4 b0 = sc[0], b1v = sc[1], b2 = sc[2], b3 = sc[3];
    const float dot = a0.x * b0.x + a0.y * b0.y + a0.z * b0.z + a0.w * b0.w
                    + a1.x * b1v.x + a1.y * b1v.y + a1.z * b1v.z + a1.w * b1v.w
                    + a2.x * b2.x + a2.y * b2.y + a2.z * b2.z + a2.w * b2.w
                    + a3.x * b3.x + a3.y * b3.y + a3.z * b3.z + a3.w * b3.w;
    ltp += v * dot;
    lnl[0] += v * b0.x;  lnl[1] += v * b0.y;  lnl[2] += v * b0.z;  lnl[3] += v * b0.w;
    lnl[4] += v * b1v.x; lnl[5] += v * b1v.y; lnl[6] += v * b1v.z; lnl[7] += v * b1v.w;
    lnl[8] += v * b2.x;  lnl[9] += v * b2.y;  lnl[10] += v * b2.z; lnl[11] += v * b2.w;
    lnl[12] += v * b3.x; lnl[13] += v * b3.y; lnl[14] += v * b3.z; lnl[15] += v * b3.w;
  }
#pragma unroll
  for (int off = 32; off; off >>= 1) {
    ltp += __shfl_xor(ltp, off);
#pragma unroll
    for (int k = 0; k < KC; ++k) lnl[k] += __shfl_xor(lnl[k], off);
  }
  __shared__ float wred[4][KC + 1];
  const int wave = threadIdx.x >> 6, lane = threadIdx.x & 63;
  if (lane == 0) {
    wred[wave][0] = ltp;
#pragma unroll
    for (int k = 0; k < KC; ++k) wred[wave][1 + k] = lnl[k];
  }
  __syncthreads();
  if (threadIdx.x < KC + 1) {
    const float s = wred[0][threadIdx.x] + wred[1][threadIdx.x] + wred[2][threadIdx.x] + wred[3][threadIdx.x];
    if (threadIdx.x == 0) atomicAdd(tp, s);
    else atomicAdd(&nl[threadIdx.x - 1], s);
  }
}

// ---- final scalar assembly ----
// scal layout: [0]=dotAG, [1]=tp, [2..17]=nl, [18..33]=cs
__global__ void k_final(const float* __restrict__ exptot, const float* __restrict__ augtot,
                        const float* __restrict__ scal, float* __restrict__ out) {
  const int d = threadIdx.x;
  const float L = logf(exptot[d]);
  const float sa = augtot[d];
  __shared__ float red[DH];
  red[d] = L * sa;
  __syncthreads();
  for (int off = 128; off; off >>= 1) {
    if (d < off) red[d] += red[d + off];
    __syncthreads();
  }
  if (d == 0) {
    const float sumLA = red[0];
    const float dotAG = scal[0];
    const float tp = scal[1];
    float nl2 = 0.f, cs2 = 0.f;
#pragma unroll
    for (int k = 0; k < KC; ++k) {
      nl2 += scal[2 + k] * scal[2 + k];
      cs2 += scal[18 + k] * scal[18 + k];
    }
    const float fE = (float)NE;
    const float con = -(dotAG - sumLA) / (float)DH;
    const float trn = nl2 / (2.f * fE);
    const float spectral = -(tp - trn) / (2.f * fE);
    const float cluster = (sqrtf(cs2) / (float)N_NODES * 4.f - 1.f);
    out[0] = spectral + cluster + 0.5f * con;
  }
}

extern "C" void kernel_launch(void* const* d_in, const int* in_sizes, int n_in,
                              void* d_out, int out_size, void* d_ws, size_t ws_size,
                              hipStream_t stream) {
  const float* features = (const float*)d_in[0];
  const float* augf     = (const float*)d_in[1];
  const int*   grow     = (const int*)d_in[2];
  const int*   gcol     = (const int*)d_in[3];
  const float* gvals    = (const float*)d_in[4];
  const float* gnv      = (const float*)d_in[5];
  const float* W1       = (const float*)d_in[8];
  const float* b1       = (const float*)d_in[9];
  const float* Wt       = (const float*)d_in[10];
  const float* bt       = (const float*)d_in[11];

  char* ws = (char*)d_ws;
  size_t off = 0;
  auto alloc = [&](size_t bytes) -> void* {
    void* p = ws + off;
    off = (off + bytes + 255) & ~(size_t)255;
    return p;
  };
  unsigned short* Wbf  = (unsigned short*)alloc((size_t)DH * KPAD * 2);
  unsigned short* XWs  = (unsigned short*)alloc((size_t)16 * MPAD * SLICE_COLS * 2);
  unsigned short* O    = (unsigned short*)alloc((size_t)2 * N_NODES * DH * 2);
  float* S       = (float*)alloc((size_t)N_NODES * KC * 4);
  int*   ecol    = (int*)alloc((size_t)NE * 4);
  float* eval    = (float*)alloc((size_t)NE * 4);
  int*   row_ptr = (int*)alloc((size_t)(N_NODES + 1) * 4);
  int*   cursor  = (int*)alloc((size_t)N_NODES * 4);
  int*   counts  = (int*)alloc((size_t)N_NODES * 4);
  float* exptot  = (float*)alloc((size_t)DH * 4);   // contiguous zero region:
  float* augtot  = (float*)alloc((size_t)DH * 4);   //   exptot | augtot | scal
  float* scal    = (float*)alloc(64 * 4);
  if (off > ws_size) return;  // workspace too small: fail loudly, no OOB

  hipMemsetAsync(counts, 0, (size_t)N_NODES * 4, stream);
  hipMemsetAsync(exptot, 0, (size_t)DH * 4 * 2 + 64 * 4, stream);

  // W1 -> bf16, pre-swizzled for the GEMM's B-staging
  k_cvt_w1<<<64, 256, 0, stream>>>(W1, Wbf);

  // CSR build
  k_count<<<(NE + 255) / 256, 256, 0, stream>>>(grow, counts);
  k_scan<<<1, 1024, 0, stream>>>(counts, row_ptr, cursor);
  k_scatter<<<(NE + 255) / 256, 256, 0, stream>>>(grow, gcol, gnv, cursor, ecol, eval);

  // fused-conversion GEMM over both matrices -> slice-major XWs (coalesced C)
  k_gemm_fused<<<M2 / 128, 512, 0, stream>>>(features, augf, Wbf, XWs);

  // XCD-sliced SpMM, one phase per launch (per-XCD working set = 3.2MB slice)
  k_spmm_slice<<<SPMM_BLOCKS, 256, 0, stream>>>(row_ptr, ecol, eval,
                                                XWs, b1, O);
  k_spmm_slice<<<SPMM_BLOCKS, 256, 0, stream>>>(row_ptr, ecol, eval,
                                                XWs + (size_t)NPAIR * MPAD * SLICE_COLS,
                                                b1, O + (size_t)N_NODES * DH);

  // epilogue: S softmax + global partials
  k_post<<<POST_BLOCKS, 256, 0, stream>>>(O, Wt, bt, S, exptot, augtot,
                                          scal + 18, scal + 0);

  // graph stats on assignments
  k_edge<<<512, 256, 0, stream>>>(grow, gcol, gvals, S, scal + 2, scal + 1);

  // final scalar
  k_final<<<1, 256, 0, stream>>>(exptot, augtot, scal, (float*)d_out);
}

// Round 12
// 488.665 us; speedup vs baseline: 1.4737x; 1.2258x over previous
//
#include <hip/hip_runtime.h>
#include <math.h>

// Problem constants (fixed by reference)
#define N_NODES 50000
#define N_FEAT  500
#define DH      256
#define KC      16
#define NE      800000
#define KPAD    512     // N_FEAT padded to MFMA K multiple
#define MPAD    50048   // 391 * 128 (GEMM M tiles)
#define M2      (2 * MPAD)
#define SLICE_COLS 32   // D-slice per XCD: 50048*32*2B = 3.2MB fits 4MB L2
#define NPAIR   8       // 8 col-slices per matrix
#define SPMM_BLOCKS 2048
#define ROWS_PER_BLK 196  // ceil(50000/256)
#define POST_BLOCKS 2048
#define SCAN_BLOCKS 196   // ceil(50000/256)

#define R16(X) X(0) X(1) X(2) X(3) X(4) X(5) X(6) X(7) \
               X(8) X(9) X(10) X(11) X(12) X(13) X(14) X(15)

typedef __attribute__((ext_vector_type(8))) short short8;
typedef __attribute__((ext_vector_type(4))) float f32x4;

__device__ __forceinline__ unsigned short f2bf(float f) {
  unsigned u = __float_as_uint(f);
  u += 0x7FFFu + ((u >> 16) & 1u);   // RNE
  return (unsigned short)(u >> 16);
}

__device__ __forceinline__ float bf2f(unsigned short u) {
  return __uint_as_float((unsigned)u << 16);
}

__device__ __forceinline__ float selu_f(float x) {
  return 1.0507009873554805f * (x > 0.f ? x : 1.6732632423543772f * expm1f(x));
}

__device__ __forceinline__ void gload16(const void* g, void* l) {
  __builtin_amdgcn_global_load_lds(
      (const __attribute__((address_space(1))) unsigned int*)g,
      (__attribute__((address_space(3))) unsigned int*)l, 16, 0, 0);
}

// ---- W1 f32 -> bf16, zero-padded AND pre-swizzled so that the GEMM's linear
//      global_load_lds lands each 16B chunk at its XOR-swizzled LDS slot. ----
__global__ void k_cvt_w1(const float* __restrict__ in, unsigned short* __restrict__ out) {
  const int idx = blockIdx.x * 256 + threadIdx.x;   // one 16B chunk each
  if (idx >= DH * (KPAD / 8)) return;
  const int row = idx >> 6;          // 0..255
  const int cc  = idx & 63;          // out chunk within row
  const int scc = (cc & ~7) | ((cc & 7) ^ (row & 7));   // source chunk
  const int c0 = scc * 8;
  short8 w;
#pragma unroll
  for (int j = 0; j < 8; ++j) {
    const int col = c0 + j;
    w[j] = (col < N_FEAT) ? (short)f2bf(in[(size_t)row * N_FEAT + col]) : (short)0;
  }
  *(short8*)(out + (size_t)row * KPAD + cc * 8) = w;
}

// ---- Fused f32->bf16 GEMM, T2-swizzled LDS (R11: conflicts 10.6M -> ~0). ----
__global__ __launch_bounds__(512, 2) void k_gemm_fused(
    const float* __restrict__ Af, const float* __restrict__ Aa,
    const unsigned short* __restrict__ Wbf, unsigned short* __restrict__ XWs) {
  __shared__ short As[128 * 64];
  __shared__ short Bs[256 * 64];
  const int t = threadIdx.x;
  const int lane = t & 63, wave = t >> 6;
  const int wr = (wave >> 2) * 64, wc = (wave & 3) * 64;
  const int bm = blockIdx.x * 128;
  const bool isaug = bm >= MPAD;
  const float* __restrict__ src = isaug ? Aa : Af;
  const int row0 = isaug ? bm - MPAD : bm;
  const int lr = lane & 15, lk = (lane >> 4) * 8;
  const int rsw = (lr & 7) * 8;            // read-side swizzle (const per lane)
  const int ar = t >> 3, ac = (t & 7) * 8;
  const int aw = ac ^ ((ar & 7) * 8);      // A-stage write swizzle
  f32x4 acc[4][4] = {};
  for (int kb = 0; kb < KPAD; kb += 64) {
    // A loads first: branchless, all 4 in flight
    float4 ua[2][2];
#pragma unroll
    for (int h = 0; h < 2; ++h) {
      const int gr = row0 + ar + h * 64;
      const bool vr = gr < N_NODES;
      const float* arow = src + (size_t)(vr ? gr : 0) * N_FEAT;
      const int c = kb + ac;
      ua[h][0] = *(const float4*)(arow + min(c, N_FEAT - 4));
      ua[h][1] = *(const float4*)(arow + min(c + 4, N_FEAT - 4));
    }
    // B stage: 256x64 bf16 via global_load_lds (source pre-swizzled)
#pragma unroll
    for (int i = 0; i < 4; ++i) {
      const int chunk = i * 512 + t;
      const int rb = chunk >> 3, sub = (chunk & 7) * 8;
      gload16(Wbf + (size_t)rb * KPAD + kb + sub, (void*)(Bs + (size_t)chunk * 8));
    }
    // mask + pack + swizzled ds_write
#pragma unroll
    for (int h = 0; h < 2; ++h) {
      const int gr = row0 + ar + h * 64;
      const bool vr = gr < N_NODES;
      const int c = kb + ac;
      const bool ok0 = vr && (c < N_FEAT);
      const bool ok1 = vr && (c + 4 < N_FEAT);
      float4 u0 = ua[h][0], u1 = ua[h][1];
      u0.x = ok0 ? u0.x : 0.f; u0.y = ok0 ? u0.y : 0.f;
      u0.z = ok0 ? u0.z : 0.f; u0.w = ok0 ? u0.w : 0.f;
      u1.x = ok1 ? u1.x : 0.f; u1.y = ok1 ? u1.y : 0.f;
      u1.z = ok1 ? u1.z : 0.f; u1.w = ok1 ? u1.w : 0.f;
      short8 w;
      w[0] = (short)f2bf(u0.x); w[1] = (short)f2bf(u0.y);
      w[2] = (short)f2bf(u0.z); w[3] = (short)f2bf(u0.w);
      w[4] = (short)f2bf(u1.x); w[5] = (short)f2bf(u1.y);
      w[6] = (short)f2bf(u1.z); w[7] = (short)f2bf(u1.w);
      *(short8*)(As + (size_t)(ar + h * 64) * 64 + aw) = w;
    }
    __syncthreads();
#pragma unroll
    for (int kk = 0; kk < 64; kk += 32) {
      short8 af[4], bfr[4];
#pragma unroll
      for (int mi = 0; mi < 4; ++mi)
        af[mi] = *(const short8*)(As + (wr + mi * 16 + lr) * 64 + ((kk + lk) ^ rsw));
#pragma unroll
      for (int n = 0; n < 4; ++n)
        bfr[n] = *(const short8*)(Bs + (wc + n * 16 + lr) * 64 + ((kk + lk) ^ rsw));
#pragma unroll
      for (int mi = 0; mi < 4; ++mi)
#pragma unroll
        for (int n = 0; n < 4; ++n)
          acc[mi][n] = __builtin_amdgcn_mfma_f32_16x16x32_bf16(af[mi], bfr[n], acc[mi][n], 0, 0, 0);
    }
    __syncthreads();
  }
  // ---- coalesced C-write: 4 passes of 64 cols via As (swizzled staging) ----
  const int crow = (lane >> 4) * 4, ccol = lane & 15;
  const int phb8 = isaug ? NPAIR : 0;
  const int snode = t >> 2, ssub = t & 3;   // 128 nodes x 4 16B-chunks
  const int csw = (snode & 7) * 8;          // C-stage read swizzle
#pragma unroll
  for (int cb = 0; cb < 4; ++cb) {
    if ((wave & 3) == cb) {   // the 2 waves owning cols [cb*64, cb*64+64)
#pragma unroll
      for (int mi = 0; mi < 4; ++mi)
#pragma unroll
        for (int n = 0; n < 4; ++n)
#pragma unroll
          for (int r = 0; r < 4; ++r)
            As[(wr + mi * 16 + crow + r) * 64 +
               ((n * 16 + ccol) ^ (((crow + r) & 7) * 8))] =
                (short)f2bf(acc[mi][n][r]);
    }
    __syncthreads();
#pragma unroll
    for (int p2 = 0; p2 < 2; ++p2) {
      const int pair = phb8 + cb * 2 + p2;
      const short8 vv = *(const short8*)(As + snode * 64 + ((p2 * 32 + ssub * 8) ^ csw));
      *(short8*)(XWs + ((size_t)pair * MPAD + row0 + snode) * SLICE_COLS + ssub * 8) = vv;
    }
    __syncthreads();
  }
}

// ---- CSR build ----
__global__ void k_count(const int* __restrict__ row, int* __restrict__ counts) {
  const int e = blockIdx.x * blockDim.x + threadIdx.x;
  if (e < NE) atomicAdd(&counts[row[e]], 1);
}

// Hierarchical scan (R11: single-block serial k_scan was 126us on 1 CU).
__global__ __launch_bounds__(256) void k_scan_blk(const int* __restrict__ counts,
                                                  int* __restrict__ bsum) {
  __shared__ int red[256];
  const int t = threadIdx.x;
  const int j = blockIdx.x * 256 + t;
  red[t] = (j < N_NODES) ? counts[j] : 0;
  __syncthreads();
  for (int off = 128; off; off >>= 1) {
    if (t < off) red[t] += red[t + off];
    __syncthreads();
  }
  if (t == 0) bsum[blockIdx.x] = red[0];
}

__global__ __launch_bounds__(256) void k_scan_top(const int* __restrict__ bsum,
                                                  int* __restrict__ boff) {
  __shared__ int s[256];
  const int t = threadIdx.x;
  s[t] = (t < SCAN_BLOCKS) ? bsum[t] : 0;
  __syncthreads();
  for (int off = 1; off < 256; off <<= 1) {
    const int u = (t >= off) ? s[t - off] : 0;
    __syncthreads();
    s[t] += u;
    __syncthreads();
  }
  boff[t] = (t == 0) ? 0 : s[t - 1];   // exclusive block offsets
}

__global__ __launch_bounds__(256) void k_scan_fin(const int* __restrict__ counts,
                                                  const int* __restrict__ boff,
                                                  int* __restrict__ row_ptr,
                                                  int* __restrict__ cursor) {
  __shared__ int s[256];
  const int t = threadIdx.x;
  const int j = blockIdx.x * 256 + t;
  const int v = (j < N_NODES) ? counts[j] : 0;
  s[t] = v;
  __syncthreads();
  for (int off = 1; off < 256; off <<= 1) {
    const int u = (t >= off) ? s[t - off] : 0;
    __syncthreads();
    s[t] += u;
    __syncthreads();
  }
  const int excl = boff[blockIdx.x] + s[t] - v;
  if (j < N_NODES) { row_ptr[j] = excl; cursor[j] = excl; }
  if (j == N_NODES - 1) row_ptr[N_NODES] = excl + v;
}

__global__ void k_scatter(const int* __restrict__ row, const int* __restrict__ col,
                          const float* __restrict__ gnv, int* __restrict__ cursor,
                          int* __restrict__ ecol, float* __restrict__ eval) {
  const int e = blockIdx.x * blockDim.x + threadIdx.x;
  if (e < NE) {
    const int p = atomicAdd(&cursor[row[e]], 1);
    ecol[p] = col[e];
    eval[p] = gnv[e];
  }
}

// ---- XCD-sliced SpMM + bias + selu -> O (bf16). One phase per launch. ----
__global__ __launch_bounds__(256, 4) void k_spmm_slice(
    const int* __restrict__ row_ptr, const int* __restrict__ ecol, const float* __restrict__ eval,
    const unsigned short* __restrict__ XWp,  // phase base: XWs + ph*8*MPAD*32
    const float* __restrict__ b1,
    unsigned short* __restrict__ Ob) {       // phase base: O + ph*N*DH
  const int slice = blockIdx.x & 7;
  const int rblk  = blockIdx.x >> 3;
  const int r0 = rblk * ROWS_PER_BLK;
  const int r1 = min(r0 + ROWS_PER_BLK, N_NODES);
  const int wave = threadIdx.x >> 6, lane = threadIdx.x & 63;
  const int g = lane >> 2, sub = lane & 3;
  const int scol = slice * SLICE_COLS + sub * 8;

  const float4 b0 = *(const float4*)(b1 + scol);
  const float4 b4 = *(const float4*)(b1 + scol + 4);
  const unsigned short* __restrict__ Xb =
      XWp + (size_t)slice * MPAD * SLICE_COLS + sub * 8;

  for (int rb = r0; rb < r1; rb += 64) {
    const int row = rb + wave * 16 + g;
    if (row >= r1) continue;
    const int s = row_ptr[row], e = row_ptr[row + 1];
    float acc[8] = {0.f, 0.f, 0.f, 0.f, 0.f, 0.f, 0.f, 0.f};
    int p = s;
    for (; p + 1 < e; p += 2) {
      const int   c0 = ecol[p],  c1 = ecol[p + 1];
      const float v0 = eval[p],  v1 = eval[p + 1];
      const short8 x0 = *(const short8*)(Xb + (size_t)c0 * SLICE_COLS);
      const short8 x1 = *(const short8*)(Xb + (size_t)c1 * SLICE_COLS);
#pragma unroll
      for (int u = 0; u < 8; ++u) {
        acc[u] += v0 * bf2f((unsigned short)x0[u]);
        acc[u] += v1 * bf2f((unsigned short)x1[u]);
      }
    }
    if (p < e) {
      const int   c0 = ecol[p];
      const float v0 = eval[p];
      const short8 x0 = *(const short8*)(Xb + (size_t)c0 * SLICE_COLS);
#pragma unroll
      for (int u = 0; u < 8; ++u) acc[u] += v0 * bf2f((unsigned short)x0[u]);
    }
    short8 o;
    o[0] = (short)f2bf(selu_f(acc[0] + b0.x));
    o[1] = (short)f2bf(selu_f(acc[1] + b0.y));
    o[2] = (short)f2bf(selu_f(acc[2] + b0.z));
    o[3] = (short)f2bf(selu_f(acc[3] + b0.w));
    o[4] = (short)f2bf(selu_f(acc[4] + b4.x));
    o[5] = (short)f2bf(selu_f(acc[5] + b4.y));
    o[6] = (short)f2bf(selu_f(acc[6] + b4.z));
    o[7] = (short)f2bf(selu_f(acc[7] + b4.w));
    *(short8*)(Ob + (size_t)row * DH + scol) = o;
  }
}

// ---- Epilogue over O: S softmax, exp-colsums, aug-colsums, dot, cluster sizes. ----
__global__ __launch_bounds__(256, 2) void k_post(
    const unsigned short* __restrict__ O, const float* __restrict__ Wt,
    const float* __restrict__ bt, float* __restrict__ S,
    float* __restrict__ exptot, float* __restrict__ augtot,
    float* __restrict__ csg, float* __restrict__ dotAG) {
  __shared__ float expacc[DH];
  __shared__ float augacc[DH];
  __shared__ float csacc[KC];
  __shared__ float dacc;
  expacc[threadIdx.x] = 0.f;
  augacc[threadIdx.x] = 0.f;
  if (threadIdx.x < KC) csacc[threadIdx.x] = 0.f;
  if (threadIdx.x == 0) dacc = 0.f;
  __syncthreads();

  const int wave = threadIdx.x >> 6, lane = threadIdx.x & 63;
  const int c0 = lane * 4;
  const unsigned short* Of = O;
  const unsigned short* Oa = O + (size_t)N_NODES * DH;

  float lexp0 = 0.f, lexp1 = 0.f, lexp2 = 0.f, lexp3 = 0.f;
  float laug0 = 0.f, laug1 = 0.f, laug2 = 0.f, laug3 = 0.f;
  float ldot = 0.f, lcs = 0.f;
#define LDBT(K) const float bt_##K = bt[K];
  R16(LDBT)
#undef LDBT

  for (int i = blockIdx.x * 4 + wave; i < N_NODES; i += POST_BLOCKS * 4) {
    const ushort4 fu = *(const ushort4*)(Of + (size_t)i * DH + c0);
    const ushort4 au = *(const ushort4*)(Oa + (size_t)i * DH + c0);
    const float of0 = bf2f(fu.x), of1 = bf2f(fu.y), of2 = bf2f(fu.z), of3 = bf2f(fu.w);
    const float oa0 = bf2f(au.x), oa1 = bf2f(au.y), oa2 = bf2f(au.z), oa3 = bf2f(au.w);
    lexp0 += expf(of0); lexp1 += expf(of1); lexp2 += expf(of2); lexp3 += expf(of3);
    laug0 += oa0; laug1 += oa1; laug2 += oa2; laug3 += oa3;
    ldot += of0 * oa0 + of1 * oa1 + of2 * oa2 + of3 * oa3;

#define DOT(K) float l##K; { const float4 w = *(const float4*)(Wt + K * DH + c0); \
                             l##K = of0 * w.x + of1 * w.y + of2 * w.z + of3 * w.w; }
    R16(DOT)
#undef DOT
#pragma unroll
    for (int off = 32; off; off >>= 1) {
#define SHF(K) l##K += __shfl_xor(l##K, off);
      R16(SHF)
#undef SHF
    }
#define BIAS(K) l##K += bt_##K;
    R16(BIAS)
#undef BIAS
    float mx = l0;
#define MX(K) mx = fmaxf(mx, l##K);
    R16(MX)
#undef MX
    float se = 0.f;
#define EXPK(K) l##K = expf(l##K - mx); se += l##K;
    R16(EXPK)
#undef EXPK
    const float inv = 1.f / se;
    float myv = 0.f;
#define SEL(K) if (lane == K) myv = l##K;
    R16(SEL)
#undef SEL
    if (lane < KC) {
      const float sv = myv * inv;
      S[(size_t)i * KC + lane] = sv;
      lcs += sv;
    }
  }

#pragma unroll
  for (int off = 32; off; off >>= 1) ldot += __shfl_xor(ldot, off);
  if (lane == 0) atomicAdd(&dacc, ldot);
  atomicAdd(&expacc[c0 + 0], lexp0);
  atomicAdd(&expacc[c0 + 1], lexp1);
  atomicAdd(&expacc[c0 + 2], lexp2);
  atomicAdd(&expacc[c0 + 3], lexp3);
  atomicAdd(&augacc[c0 + 0], laug0);
  atomicAdd(&augacc[c0 + 1], laug1);
  atomicAdd(&augacc[c0 + 2], laug2);
  atomicAdd(&augacc[c0 + 3], laug3);
  if (lane < KC) atomicAdd(&csacc[lane], lcs);
  __syncthreads();
  atomicAdd(&exptot[threadIdx.x], expacc[threadIdx.x]);
  atomicAdd(&augtot[threadIdx.x], augacc[threadIdx.x]);
  if (threadIdx.x < KC) atomicAdd(&csg[threadIdx.x], csacc[threadIdx.x]);
  if (threadIdx.x == 0) atomicAdd(dotAG, dacc);
}

// ---- edge stats: tp = sum_e v*dot16(S[row],S[col]); nl[k] = sum_e v*S[col,k] ----
__global__ __launch_bounds__(256) void k_edge(const int* __restrict__ grow, const int* __restrict__ gcol,
                                              const float* __restrict__ gvals, const float* __restrict__ S,
                                              float* __restrict__ nl, float* __restrict__ tp) {
  float ltp = 0.f;
  float lnl[KC];
#pragma unroll
  for (int k = 0; k < KC; ++k) lnl[k] = 0.f;
  for (long e = (long)blockIdx.x * 256 + threadIdx.x; e < NE; e += (long)gridDim.x * 256) {
    const int r = grow[e], c = gcol[e];
    const float v = gvals[e];
    const float4* sr = (const float4*)(S + (size_t)r * KC);
    const float4* sc = (const float4*)(S + (size_t)c * KC);
    const float4 a0 = sr[0], a1 = sr[1], a2 = sr[2], a3 = sr[3];
    const float4 b0 = sc[0], b1v = sc[1], b2 = sc[2], b3 = sc[3];
    const float dot = a0.x * b0.x + a0.y * b0.y + a0.z * b0.z + a0.w * b0.w
                    + a1.x * b1v.x + a1.y * b1v.y + a1.z * b1v.z + a1.w * b1v.w
                    + a2.x * b2.x + a2.y * b2.y + a2.z * b2.z + a2.w * b2.w
                    + a3.x * b3.x + a3.y * b3.y + a3.z * b3.z + a3.w * b3.w;
    ltp += v * dot;
    lnl[0] += v * b0.x;  lnl[1] += v * b0.y;  lnl[2] += v * b0.z;  lnl[3] += v * b0.w;
    lnl[4] += v * b1v.x; lnl[5] += v * b1v.y; lnl[6] += v * b1v.z; lnl[7] += v * b1v.w;
    lnl[8] += v * b2.x;  lnl[9] += v * b2.y;  lnl[10] += v * b2.z; lnl[11] += v * b2.w;
    lnl[12] += v * b3.x; lnl[13] += v * b3.y; lnl[14] += v * b3.z; lnl[15] += v * b3.w;
  }
#pragma unroll
  for (int off = 32; off; off >>= 1) {
    ltp += __shfl_xor(ltp, off);
#pragma unroll
    for (int k = 0; k < KC; ++k) lnl[k] += __shfl_xor(lnl[k], off);
  }
  __shared__ float wred[4][KC + 1];
  const int wave = threadIdx.x >> 6, lane = threadIdx.x & 63;
  if (lane == 0) {
    wred[wave][0] = ltp;
#pragma unroll
    for (int k = 0; k < KC; ++k) wred[wave][1 + k] = lnl[k];
  }
  __syncthreads();
  if (threadIdx.x < KC + 1) {
    const float s = wred[0][threadIdx.x] + wred[1][threadIdx.x] + wred[2][threadIdx.x] + wred[3][threadIdx.x];
    if (threadIdx.x == 0) atomicAdd(tp, s);
    else atomicAdd(&nl[threadIdx.x - 1], s);
  }
}

// ---- final scalar assembly ----
// scal layout: [0]=dotAG, [1]=tp, [2..17]=nl, [18..33]=cs
__global__ void k_final(const float* __restrict__ exptot, const float* __restrict__ augtot,
                        const float* __restrict__ scal, float* __restrict__ out) {
  const int d = threadIdx.x;
  const float L = logf(exptot[d]);
  const float sa = augtot[d];
  __shared__ float red[DH];
  red[d] = L * sa;
  __syncthreads();
  for (int off = 128; off; off >>= 1) {
    if (d < off) red[d] += red[d + off];
    __syncthreads();
  }
  if (d == 0) {
    const float sumLA = red[0];
    const float dotAG = scal[0];
    const float tp = scal[1];
    float nl2 = 0.f, cs2 = 0.f;
#pragma unroll
    for (int k = 0; k < KC; ++k) {
      nl2 += scal[2 + k] * scal[2 + k];
      cs2 += scal[18 + k] * scal[18 + k];
    }
    const float fE = (float)NE;
    const float con = -(dotAG - sumLA) / (float)DH;
    const float trn = nl2 / (2.f * fE);
    const float spectral = -(tp - trn) / (2.f * fE);
    const float cluster = (sqrtf(cs2) / (float)N_NODES * 4.f - 1.f);
    out[0] = spectral + cluster + 0.5f * con;
  }
}

extern "C" void kernel_launch(void* const* d_in, const int* in_sizes, int n_in,
                              void* d_out, int out_size, void* d_ws, size_t ws_size,
                              hipStream_t stream) {
  const float* features = (const float*)d_in[0];
  const float* augf     = (const float*)d_in[1];
  const int*   grow     = (const int*)d_in[2];
  const int*   gcol     = (const int*)d_in[3];
  const float* gvals    = (const float*)d_in[4];
  const float* gnv      = (const float*)d_in[5];
  const float* W1       = (const float*)d_in[8];
  const float* b1       = (const float*)d_in[9];
  const float* Wt       = (const float*)d_in[10];
  const float* bt       = (const float*)d_in[11];

  char* ws = (char*)d_ws;
  size_t off = 0;
  auto alloc = [&](size_t bytes) -> void* {
    void* p = ws + off;
    off = (off + bytes + 255) & ~(size_t)255;
    return p;
  };
  unsigned short* Wbf  = (unsigned short*)alloc((size_t)DH * KPAD * 2);
  unsigned short* XWs  = (unsigned short*)alloc((size_t)16 * MPAD * SLICE_COLS * 2);
  unsigned short* O    = (unsigned short*)alloc((size_t)2 * N_NODES * DH * 2);
  float* S       = (float*)alloc((size_t)N_NODES * KC * 4);
  int*   ecol    = (int*)alloc((size_t)NE * 4);
  float* eval    = (float*)alloc((size_t)NE * 4);
  int*   row_ptr = (int*)alloc((size_t)(N_NODES + 1) * 4);
  int*   cursor  = (int*)alloc((size_t)N_NODES * 4);
  int*   counts  = (int*)alloc((size_t)N_NODES * 4);
  int*   bsum    = (int*)alloc((size_t)256 * 4);
  int*   boff    = (int*)alloc((size_t)256 * 4);
  float* exptot  = (float*)alloc((size_t)DH * 4);   // contiguous zero region:
  float* augtot  = (float*)alloc((size_t)DH * 4);   //   exptot | augtot | scal
  float* scal    = (float*)alloc(64 * 4);
  if (off > ws_size) return;  // workspace too small: fail loudly, no OOB

  hipMemsetAsync(counts, 0, (size_t)N_NODES * 4, stream);
  hipMemsetAsync(exptot, 0, (size_t)DH * 4 * 2 + 64 * 4, stream);

  // W1 -> bf16, pre-swizzled for the GEMM's B-staging
  k_cvt_w1<<<64, 256, 0, stream>>>(W1, Wbf);

  // CSR build (hierarchical scan)
  k_count<<<(NE + 255) / 256, 256, 0, stream>>>(grow, counts);
  k_scan_blk<<<SCAN_BLOCKS, 256, 0, stream>>>(counts, bsum);
  k_scan_top<<<1, 256, 0, stream>>>(bsum, boff);
  k_scan_fin<<<SCAN_BLOCKS, 256, 0, stream>>>(counts, boff, row_ptr, cursor);
  k_scatter<<<(NE + 255) / 256, 256, 0, stream>>>(grow, gcol, gnv, cursor, ecol, eval);

  // fused-conversion GEMM over both matrices -> slice-major XWs (coalesced C)
  k_gemm_fused<<<M2 / 128, 512, 0, stream>>>(features, augf, Wbf, XWs);

  // XCD-sliced SpMM, one phase per launch (per-XCD working set = 3.2MB slice)
  k_spmm_slice<<<SPMM_BLOCKS, 256, 0, stream>>>(row_ptr, ecol, eval,
                                                XWs, b1, O);
  k_spmm_slice<<<SPMM_BLOCKS, 256, 0, stream>>>(row_ptr, ecol, eval,
                                                XWs + (size_t)NPAIR * MPAD * SLICE_COLS,
                                                b1, O + (size_t)N_NODES * DH);

  // epilogue: S softmax + global partials
  k_post<<<POST_BLOCKS, 256, 0, stream>>>(O, Wt, bt, S, exptot, augtot,
                                          scal + 18, scal + 0);

  // graph stats on assignments
  k_edge<<<512, 256, 0, stream>>>(grow, gcol, gvals, S, scal + 2, scal + 1);

  // final scalar
  k_final<<<1, 256, 0, stream>>>(exptot, augtot, scal, (float*)d_out);
}

// Round 13
// 444.844 us; speedup vs baseline: 1.6189x; 1.0985x over previous
//
#include <hip/hip_runtime.h>
#include <math.h>

// Problem constants (fixed by reference)
#define N_NODES 50000
#define N_FEAT  500
#define DH      256
#define KC      16
#define NE      800000
#define KPAD    512     // N_FEAT padded to MFMA K multiple
#define MPAD    50048   // 391 * 128 (GEMM M tiles)
#define M2      (2 * MPAD)
#define SLICE_COLS 32   // D-slice per XCD: 50048*32*2B = 3.2MB fits 4MB L2
#define NPAIR   8       // 8 col-slices per matrix
#define SPMM_BLOCKS 2048
#define ROWS_PER_BLK 196  // ceil(50000/256)
#define POST_BLOCKS 2048
#define SCAN_BLOCKS 196   // ceil(50000/256)

#define R16(X) X(0) X(1) X(2) X(3) X(4) X(5) X(6) X(7) \
               X(8) X(9) X(10) X(11) X(12) X(13) X(14) X(15)

typedef __attribute__((ext_vector_type(8))) short short8;
typedef __attribute__((ext_vector_type(4))) float f32x4;

__device__ __forceinline__ unsigned short f2bf(float f) {
  unsigned u = __float_as_uint(f);
  u += 0x7FFFu + ((u >> 16) & 1u);   // RNE
  return (unsigned short)(u >> 16);
}

__device__ __forceinline__ float bf2f(unsigned short u) {
  return __uint_as_float((unsigned)u << 16);
}

__device__ __forceinline__ float selu_f(float x) {
  return 1.0507009873554805f * (x > 0.f ? x : 1.6732632423543772f * expm1f(x));
}

__device__ __forceinline__ void gload16(const void* g, void* l) {
  __builtin_amdgcn_global_load_lds(
      (const __attribute__((address_space(1))) unsigned int*)g,
      (__attribute__((address_space(3))) unsigned int*)l, 16, 0, 0);
}

// ---- W1 f32 -> bf16, zero-padded AND pre-swizzled so that the GEMM's linear
//      global_load_lds lands each 16B chunk at its XOR-swizzled LDS slot. ----
__global__ void k_cvt_w1(const float* __restrict__ in, unsigned short* __restrict__ out) {
  const int idx = blockIdx.x * 256 + threadIdx.x;   // one 16B chunk each
  if (idx >= DH * (KPAD / 8)) return;
  const int row = idx >> 6;          // 0..255
  const int cc  = idx & 63;          // out chunk within row
  const int scc = (cc & ~7) | ((cc & 7) ^ (row & 7));   // source chunk
  const int c0 = scc * 8;
  short8 w;
#pragma unroll
  for (int j = 0; j < 8; ++j) {
    const int col = c0 + j;
    w[j] = (col < N_FEAT) ? (short)f2bf(in[(size_t)row * N_FEAT + col]) : (short)0;
  }
  *(short8*)(out + (size_t)row * KPAD + cc * 8) = w;
}

// ---- Fused f32->bf16 GEMM, T2-swizzled LDS (R11), now register-pipelined:
//      R12 profile: 0 conflicts but occupancy 18.5% (144 regs/wave -> 1
//      block/CU) and serialized per-iter A-latency. Fixes:
//      (a) launch_bounds(512,4): total regs <=128 -> 2 blocks/CU;
//      (b) A-prefetch into the SAME ua regs during the MFMA phase (ua is
//          dead there — consumed by pack before barrier 1): loads fly
//          under MFMA, drain at barrier 2, zero extra registers. ----
__global__ __launch_bounds__(512, 4) void k_gemm_fused(
    const float* __restrict__ Af, const float* __restrict__ Aa,
    const unsigned short* __restrict__ Wbf, unsigned short* __restrict__ XWs) {
  __shared__ short As[128 * 64];
  __shared__ short Bs[256 * 64];
  const int t = threadIdx.x;
  const int lane = t & 63, wave = t >> 6;
  const int wr = (wave >> 2) * 64, wc = (wave & 3) * 64;
  const int bm = blockIdx.x * 128;
  const bool isaug = bm >= MPAD;
  const float* __restrict__ src = isaug ? Aa : Af;
  const int row0 = isaug ? bm - MPAD : bm;
  const int lr = lane & 15, lk = (lane >> 4) * 8;
  const int rsw = (lr & 7) * 8;            // read-side swizzle (const per lane)
  const int ar = t >> 3, ac = (t & 7) * 8;
  const int aw = ac ^ ((ar & 7) * 8);      // A-stage write swizzle
  const int gr0 = row0 + ar, gr1 = row0 + ar + 64;
  const float* const arow0 = src + (size_t)(gr0 < N_NODES ? gr0 : 0) * N_FEAT;
  const float* const arow1 = src + (size_t)(gr1 < N_NODES ? gr1 : 0) * N_FEAT;
  f32x4 acc[4][4] = {};
  float4 ua[2][2];
  // preload A(kb=0)
  {
    const int c = ac;
    ua[0][0] = *(const float4*)(arow0 + min(c, N_FEAT - 4));
    ua[0][1] = *(const float4*)(arow0 + min(c + 4, N_FEAT - 4));
    ua[1][0] = *(const float4*)(arow1 + min(c, N_FEAT - 4));
    ua[1][1] = *(const float4*)(arow1 + min(c + 4, N_FEAT - 4));
  }
  for (int kb = 0; kb < KPAD; kb += 64) {
    // B stage first (no reg dependency; latency overlaps the pack VALU)
#pragma unroll
    for (int i = 0; i < 4; ++i) {
      const int chunk = i * 512 + t;
      const int rb = chunk >> 3, sub = (chunk & 7) * 8;
      gload16(Wbf + (size_t)rb * KPAD + kb + sub, (void*)(Bs + (size_t)chunk * 8));
    }
    // pack current ua (for this kb) -> swizzled ds_write
#pragma unroll
    for (int h = 0; h < 2; ++h) {
      const int gr = h ? gr1 : gr0;
      const bool vr = gr < N_NODES;
      const int c = kb + ac;
      const bool ok0 = vr && (c < N_FEAT);
      const bool ok1 = vr && (c + 4 < N_FEAT);
      float4 u0 = ua[h][0], u1 = ua[h][1];
      u0.x = ok0 ? u0.x : 0.f; u0.y = ok0 ? u0.y : 0.f;
      u0.z = ok0 ? u0.z : 0.f; u0.w = ok0 ? u0.w : 0.f;
      u1.x = ok1 ? u1.x : 0.f; u1.y = ok1 ? u1.y : 0.f;
      u1.z = ok1 ? u1.z : 0.f; u1.w = ok1 ? u1.w : 0.f;
      short8 w;
      w[0] = (short)f2bf(u0.x); w[1] = (short)f2bf(u0.y);
      w[2] = (short)f2bf(u0.z); w[3] = (short)f2bf(u0.w);
      w[4] = (short)f2bf(u1.x); w[5] = (short)f2bf(u1.y);
      w[6] = (short)f2bf(u1.z); w[7] = (short)f2bf(u1.w);
      *(short8*)(As + (size_t)(ar + h * 64) * 64 + aw) = w;
    }
    __syncthreads();
    // prefetch next A into the SAME ua regs (dead until next pack);
    // loads stay in flight across the MFMA phase below
    if (kb + 64 < KPAD) {
      const int c = kb + 64 + ac;
      ua[0][0] = *(const float4*)(arow0 + min(c, N_FEAT - 4));
      ua[0][1] = *(const float4*)(arow0 + min(c + 4, N_FEAT - 4));
      ua[1][0] = *(const float4*)(arow1 + min(c, N_FEAT - 4));
      ua[1][1] = *(const float4*)(arow1 + min(c + 4, N_FEAT - 4));
    }
#pragma unroll
    for (int kk = 0; kk < 64; kk += 32) {
      short8 bfr[4];
#pragma unroll
      for (int n = 0; n < 4; ++n)
        bfr[n] = *(const short8*)(Bs + (wc + n * 16 + lr) * 64 + ((kk + lk) ^ rsw));
#pragma unroll
      for (int mi = 0; mi < 4; ++mi) {
        const short8 a = *(const short8*)(As + (wr + mi * 16 + lr) * 64 + ((kk + lk) ^ rsw));
#pragma unroll
        for (int n = 0; n < 4; ++n)
          acc[mi][n] = __builtin_amdgcn_mfma_f32_16x16x32_bf16(a, bfr[n], acc[mi][n], 0, 0, 0);
      }
    }
    __syncthreads();
  }
  // ---- coalesced C-write: 4 passes of 64 cols via As (swizzled staging) ----
  const int crow = (lane >> 4) * 4, ccol = lane & 15;
  const int phb8 = isaug ? NPAIR : 0;
  const int snode = t >> 2, ssub = t & 3;   // 128 nodes x 4 16B-chunks
  const int csw = (snode & 7) * 8;          // C-stage read swizzle
#pragma unroll
  for (int cb = 0; cb < 4; ++cb) {
    if ((wave & 3) == cb) {   // the 2 waves owning cols [cb*64, cb*64+64)
#pragma unroll
      for (int mi = 0; mi < 4; ++mi)
#pragma unroll
        for (int n = 0; n < 4; ++n)
#pragma unroll
          for (int r = 0; r < 4; ++r)
            As[(wr + mi * 16 + crow + r) * 64 +
               ((n * 16 + ccol) ^ (((crow + r) & 7) * 8))] =
                (short)f2bf(acc[mi][n][r]);
    }
    __syncthreads();
#pragma unroll
    for (int p2 = 0; p2 < 2; ++p2) {
      const int pair = phb8 + cb * 2 + p2;
      const short8 vv = *(const short8*)(As + snode * 64 + ((p2 * 32 + ssub * 8) ^ csw));
      *(short8*)(XWs + ((size_t)pair * MPAD + row0 + snode) * SLICE_COLS + ssub * 8) = vv;
    }
    __syncthreads();
  }
}

// ---- CSR build ----
__global__ void k_count(const int* __restrict__ row, int* __restrict__ counts) {
  const int e = blockIdx.x * blockDim.x + threadIdx.x;
  if (e < NE) atomicAdd(&counts[row[e]], 1);
}

// Hierarchical scan (R11: single-block serial k_scan was 126us on 1 CU).
__global__ __launch_bounds__(256) void k_scan_blk(const int* __restrict__ counts,
                                                  int* __restrict__ bsum) {
  __shared__ int red[256];
  const int t = threadIdx.x;
  const int j = blockIdx.x * 256 + t;
  red[t] = (j < N_NODES) ? counts[j] : 0;
  __syncthreads();
  for (int off = 128; off; off >>= 1) {
    if (t < off) red[t] += red[t + off];
    __syncthreads();
  }
  if (t == 0) bsum[blockIdx.x] = red[0];
}

__global__ __launch_bounds__(256) void k_scan_top(const int* __restrict__ bsum,
                                                  int* __restrict__ boff) {
  __shared__ int s[256];
  const int t = threadIdx.x;
  s[t] = (t < SCAN_BLOCKS) ? bsum[t] : 0;
  __syncthreads();
  for (int off = 1; off < 256; off <<= 1) {
    const int u = (t >= off) ? s[t - off] : 0;
    __syncthreads();
    s[t] += u;
    __syncthreads();
  }
  boff[t] = (t == 0) ? 0 : s[t - 1];   // exclusive block offsets
}

__global__ __launch_bounds__(256) void k_scan_fin(const int* __restrict__ counts,
                                                  const int* __restrict__ boff,
                                                  int* __restrict__ row_ptr,
                                                  int* __restrict__ cursor) {
  __shared__ int s[256];
  const int t = threadIdx.x;
  const int j = blockIdx.x * 256 + t;
  const int v = (j < N_NODES) ? counts[j] : 0;
  s[t] = v;
  __syncthreads();
  for (int off = 1; off < 256; off <<= 1) {
    const int u = (t >= off) ? s[t - off] : 0;
    __syncthreads();
    s[t] += u;
    __syncthreads();
  }
  const int excl = boff[blockIdx.x] + s[t] - v;
  if (j < N_NODES) { row_ptr[j] = excl; cursor[j] = excl; }
  if (j == N_NODES - 1) row_ptr[N_NODES] = excl + v;
}

// packed (col, val) scatter: one 8B store per edge instead of two 4B stores
__global__ void k_scatter(const int* __restrict__ row, const int* __restrict__ col,
                          const float* __restrict__ gnv, int* __restrict__ cursor,
                          int2* __restrict__ epack) {
  const int e = blockIdx.x * blockDim.x + threadIdx.x;
  if (e < NE) {
    const int p = atomicAdd(&cursor[row[e]], 1);
    epack[p] = make_int2(col[e], __float_as_int(gnv[e]));
  }
}

// ---- XCD-sliced SpMM + bias + selu -> O (bf16). One phase per launch. ----
__global__ __launch_bounds__(256, 4) void k_spmm_slice(
    const int* __restrict__ row_ptr, const int2* __restrict__ epack,
    const unsigned short* __restrict__ XWp,  // phase base: XWs + ph*8*MPAD*32
    const float* __restrict__ b1,
    unsigned short* __restrict__ Ob) {       // phase base: O + ph*N*DH
  const int slice = blockIdx.x & 7;
  const int rblk  = blockIdx.x >> 3;
  const int r0 = rblk * ROWS_PER_BLK;
  const int r1 = min(r0 + ROWS_PER_BLK, N_NODES);
  const int wave = threadIdx.x >> 6, lane = threadIdx.x & 63;
  const int g = lane >> 2, sub = lane & 3;
  const int scol = slice * SLICE_COLS + sub * 8;

  const float4 b0 = *(const float4*)(b1 + scol);
  const float4 b4 = *(const float4*)(b1 + scol + 4);
  const unsigned short* __restrict__ Xb =
      XWp + (size_t)slice * MPAD * SLICE_COLS + sub * 8;

  for (int rb = r0; rb < r1; rb += 64) {
    const int row = rb + wave * 16 + g;
    if (row >= r1) continue;
    const int s = row_ptr[row], e = row_ptr[row + 1];
    float acc[8] = {0.f, 0.f, 0.f, 0.f, 0.f, 0.f, 0.f, 0.f};
    int p = s;
    for (; p + 1 < e; p += 2) {
      const int2 e0 = epack[p], e1 = epack[p + 1];
      const float v0 = __int_as_float(e0.y), v1 = __int_as_float(e1.y);
      const short8 x0 = *(const short8*)(Xb + (size_t)e0.x * SLICE_COLS);
      const short8 x1 = *(const short8*)(Xb + (size_t)e1.x * SLICE_COLS);
#pragma unroll
      for (int u = 0; u < 8; ++u) {
        acc[u] += v0 * bf2f((unsigned short)x0[u]);
        acc[u] += v1 * bf2f((unsigned short)x1[u]);
      }
    }
    if (p < e) {
      const int2 e0 = epack[p];
      const float v0 = __int_as_float(e0.y);
      const short8 x0 = *(const short8*)(Xb + (size_t)e0.x * SLICE_COLS);
#pragma unroll
      for (int u = 0; u < 8; ++u) acc[u] += v0 * bf2f((unsigned short)x0[u]);
    }
    short8 o;
    o[0] = (short)f2bf(selu_f(acc[0] + b0.x));
    o[1] = (short)f2bf(selu_f(acc[1] + b0.y));
    o[2] = (short)f2bf(selu_f(acc[2] + b0.z));
    o[3] = (short)f2bf(selu_f(acc[3] + b0.w));
    o[4] = (short)f2bf(selu_f(acc[4] + b4.x));
    o[5] = (short)f2bf(selu_f(acc[5] + b4.y));
    o[6] = (short)f2bf(selu_f(acc[6] + b4.z));
    o[7] = (short)f2bf(selu_f(acc[7] + b4.w));
    *(short8*)(Ob + (size_t)row * DH + scol) = o;
  }
}

// ---- Epilogue over O: S softmax, exp-colsums, aug-colsums, dot, cluster sizes. ----
__global__ __launch_bounds__(256, 2) void k_post(
    const unsigned short* __restrict__ O, const float* __restrict__ Wt,
    const float* __restrict__ bt, float* __restrict__ S,
    float* __restrict__ exptot, float* __restrict__ augtot,
    float* __restrict__ csg, float* __restrict__ dotAG) {
  __shared__ float expacc[DH];
  __shared__ float augacc[DH];
  __shared__ float csacc[KC];
  __shared__ float dacc;
  expacc[threadIdx.x] = 0.f;
  augacc[threadIdx.x] = 0.f;
  if (threadIdx.x < KC) csacc[threadIdx.x] = 0.f;
  if (threadIdx.x == 0) dacc = 0.f;
  __syncthreads();

  const int wave = threadIdx.x >> 6, lane = threadIdx.x & 63;
  const int c0 = lane * 4;
  const unsigned short* Of = O;
  const unsigned short* Oa = O + (size_t)N_NODES * DH;

  float lexp0 = 0.f, lexp1 = 0.f, lexp2 = 0.f, lexp3 = 0.f;
  float laug0 = 0.f, laug1 = 0.f, laug2 = 0.f, laug3 = 0.f;
  float ldot = 0.f, lcs = 0.f;
#define LDBT(K) const float bt_##K = bt[K];
  R16(LDBT)
#undef LDBT

  for (int i = blockIdx.x * 4 + wave; i < N_NODES; i += POST_BLOCKS * 4) {
    const ushort4 fu = *(const ushort4*)(Of + (size_t)i * DH + c0);
    const ushort4 au = *(const ushort4*)(Oa + (size_t)i * DH + c0);
    const float of0 = bf2f(fu.x), of1 = bf2f(fu.y), of2 = bf2f(fu.z), of3 = bf2f(fu.w);
    const float oa0 = bf2f(au.x), oa1 = bf2f(au.y), oa2 = bf2f(au.z), oa3 = bf2f(au.w);
    lexp0 += expf(of0); lexp1 += expf(of1); lexp2 += expf(of2); lexp3 += expf(of3);
    laug0 += oa0; laug1 += oa1; laug2 += oa2; laug3 += oa3;
    ldot += of0 * oa0 + of1 * oa1 + of2 * oa2 + of3 * oa3;

#define DOT(K) float l##K; { const float4 w = *(const float4*)(Wt + K * DH + c0); \
                             l##K = of0 * w.x + of1 * w.y + of2 * w.z + of3 * w.w; }
    R16(DOT)
#undef DOT
#pragma unroll
    for (int off = 32; off; off >>= 1) {
#define SHF(K) l##K += __shfl_xor(l##K, off);
      R16(SHF)
#undef SHF
    }
#define BIAS(K) l##K += bt_##K;
    R16(BIAS)
#undef BIAS
    float mx = l0;
#define MX(K) mx = fmaxf(mx, l##K);
    R16(MX)
#undef MX
    float se = 0.f;
#define EXPK(K) l##K = expf(l##K - mx); se += l##K;
    R16(EXPK)
#undef EXPK
    const float inv = 1.f / se;
    float myv = 0.f;
#define SEL(K) if (lane == K) myv = l##K;
    R16(SEL)
#undef SEL
    if (lane < KC) {
      const float sv = myv * inv;
      S[(size_t)i * KC + lane] = sv;
      lcs += sv;
    }
  }

#pragma unroll
  for (int off = 32; off; off >>= 1) ldot += __shfl_xor(ldot, off);
  if (lane == 0) atomicAdd(&dacc, ldot);
  atomicAdd(&expacc[c0 + 0], lexp0);
  atomicAdd(&expacc[c0 + 1], lexp1);
  atomicAdd(&expacc[c0 + 2], lexp2);
  atomicAdd(&expacc[c0 + 3], lexp3);
  atomicAdd(&augacc[c0 + 0], laug0);
  atomicAdd(&augacc[c0 + 1], laug1);
  atomicAdd(&augacc[c0 + 2], laug2);
  atomicAdd(&augacc[c0 + 3], laug3);
  if (lane < KC) atomicAdd(&csacc[lane], lcs);
  __syncthreads();
  atomicAdd(&exptot[threadIdx.x], expacc[threadIdx.x]);
  atomicAdd(&augtot[threadIdx.x], augacc[threadIdx.x]);
  if (threadIdx.x < KC) atomicAdd(&csg[threadIdx.x], csacc[threadIdx.x]);
  if (threadIdx.x == 0) atomicAdd(dotAG, dacc);
}

// ---- edge stats: tp = sum_e v*dot16(S[row],S[col]); nl[k] = sum_e v*S[col,k] ----
__global__ __launch_bounds__(256) void k_edge(const int* __restrict__ grow, const int* __restrict__ gcol,
                                              const float* __restrict__ gvals, const float* __restrict__ S,
                                              float* __restrict__ nl, float* __restrict__ tp) {
  float ltp = 0.f;
  float lnl[KC];
#pragma unroll
  for (int k = 0; k < KC; ++k) lnl[k] = 0.f;
  for (long e = (long)blockIdx.x * 256 + threadIdx.x; e < NE; e += (long)gridDim.x * 256) {
    const int r = grow[e], c = gcol[e];
    const float v = gvals[e];
    const float4* sr = (const float4*)(S + (size_t)r * KC);
    const float4* sc = (const float4*)(S + (size_t)c * KC);
    const float4 a0 = sr[0], a1 = sr[1], a2 = sr[2], a3 = sr[3];
    const float4 b0 = sc[0], b1v = sc[1], b2 = sc[2], b3 = sc[3];
    const float dot = a0.x * b0.x + a0.y * b0.y + a0.z * b0.z + a0.w * b0.w
                    + a1.x * b1v.x + a1.y * b1v.y + a1.z * b1v.z + a1.w * b1v.w
                    + a2.x * b2.x + a2.y * b2.y + a2.z * b2.z + a2.w * b2.w
                    + a3.x * b3.x + a3.y * b3.y + a3.z * b3.z + a3.w * b3.w;
    ltp += v * dot;
    lnl[0] += v * b0.x;  lnl[1] += v * b0.y;  lnl[2] += v * b0.z;  lnl[3] += v * b0.w;
    lnl[4] += v * b1v.x; lnl[5] += v * b1v.y; lnl[6] += v * b1v.z; lnl[7] += v * b1v.w;
    lnl[8] += v * b2.x;  lnl[9] += v * b2.y;  lnl[10] += v * b2.z; lnl[11] += v * b2.w;
    lnl[12] += v * b3.x; lnl[13] += v * b3.y; lnl[14] += v * b3.z; lnl[15] += v * b3.w;
  }
#pragma unroll
  for (int off = 32; off; off >>= 1) {
    ltp += __shfl_xor(ltp, off);
#pragma unroll
    for (int k = 0; k < KC; ++k) lnl[k] += __shfl_xor(lnl[k], off);
  }
  __shared__ float wred[4][KC + 1];
  const int wave = threadIdx.x >> 6, lane = threadIdx.x & 63;
  if (lane == 0) {
    wred[wave][0] = ltp;
#pragma unroll
    for (int k = 0; k < KC; ++k) wred[wave][1 + k] = lnl[k];
  }
  __syncthreads();
  if (threadIdx.x < KC + 1) {
    const float s = wred[0][threadIdx.x] + wred[1][threadIdx.x] + wred[2][threadIdx.x] + wred[3][threadIdx.x];
    if (threadIdx.x == 0) atomicAdd(tp, s);
    else atomicAdd(&nl[threadIdx.x - 1], s);
  }
}

// ---- final scalar assembly ----
// scal layout: [0]=dotAG, [1]=tp, [2..17]=nl, [18..33]=cs
__global__ void k_final(const float* __restrict__ exptot, const float* __restrict__ augtot,
                        const float* __restrict__ scal, float* __restrict__ out) {
  const int d = threadIdx.x;
  const float L = logf(exptot[d]);
  const float sa = augtot[d];
  __shared__ float red[DH];
  red[d] = L * sa;
  __syncthreads();
  for (int off = 128; off; off >>= 1) {
    if (d < off) red[d] += red[d + off];
    __syncthreads();
  }
  if (d == 0) {
    const float sumLA = red[0];
    const float dotAG = scal[0];
    const float tp = scal[1];
    float nl2 = 0.f, cs2 = 0.f;
#pragma unroll
    for (int k = 0; k < KC; ++k) {
      nl2 += scal[2 + k] * scal[2 + k];
      cs2 += scal[18 + k] * scal[18 + k];
    }
    const float fE = (float)NE;
    const float con = -(dotAG - sumLA) / (float)DH;
    const float trn = nl2 / (2.f * fE);
    const float spectral = -(tp - trn) / (2.f * fE);
    const float cluster = (sqrtf(cs2) / (float)N_NODES * 4.f - 1.f);
    out[0] = spectral + cluster + 0.5f * con;
  }
}

extern "C" void kernel_launch(void* const* d_in, const int* in_sizes, int n_in,
                              void* d_out, int out_size, void* d_ws, size_t ws_size,
                              hipStream_t stream) {
  const float* features = (const float*)d_in[0];
  const float* augf     = (const float*)d_in[1];
  const int*   grow     = (const int*)d_in[2];
  const int*   gcol     = (const int*)d_in[3];
  const float* gvals    = (const float*)d_in[4];
  const float* gnv      = (const float*)d_in[5];
  const float* W1       = (const float*)d_in[8];
  const float* b1       = (const float*)d_in[9];
  const float* Wt       = (const float*)d_in[10];
  const float* bt       = (const float*)d_in[11];

  char* ws = (char*)d_ws;
  size_t off = 0;
  auto alloc = [&](size_t bytes) -> void* {
    void* p = ws + off;
    off = (off + bytes + 255) & ~(size_t)255;
    return p;
  };
  unsigned short* Wbf  = (unsigned short*)alloc((size_t)DH * KPAD * 2);
  unsigned short* XWs  = (unsigned short*)alloc((size_t)16 * MPAD * SLICE_COLS * 2);
  unsigned short* O    = (unsigned short*)alloc((size_t)2 * N_NODES * DH * 2);
  float* S       = (float*)alloc((size_t)N_NODES * KC * 4);
  int2*  epack   = (int2*)alloc((size_t)NE * 8);
  int*   row_ptr = (int*)alloc((size_t)(N_NODES + 1) * 4);
  int*   cursor  = (int*)alloc((size_t)N_NODES * 4);
  int*   counts  = (int*)alloc((size_t)N_NODES * 4);
  int*   bsum    = (int*)alloc((size_t)256 * 4);
  int*   boff    = (int*)alloc((size_t)256 * 4);
  float* exptot  = (float*)alloc((size_t)DH * 4);   // contiguous zero region:
  float* augtot  = (float*)alloc((size_t)DH * 4);   //   exptot | augtot | scal
  float* scal    = (float*)alloc(64 * 4);
  if (off > ws_size) return;  // workspace too small: fail loudly, no OOB

  hipMemsetAsync(counts, 0, (size_t)N_NODES * 4, stream);
  hipMemsetAsync(exptot, 0, (size_t)DH * 4 * 2 + 64 * 4, stream);

  // W1 -> bf16, pre-swizzled for the GEMM's B-staging
  k_cvt_w1<<<64, 256, 0, stream>>>(W1, Wbf);

  // CSR build (hierarchical scan)
  k_count<<<(NE + 255) / 256, 256, 0, stream>>>(grow, counts);
  k_scan_blk<<<SCAN_BLOCKS, 256, 0, stream>>>(counts, bsum);
  k_scan_top<<<1, 256, 0, stream>>>(bsum, boff);
  k_scan_fin<<<SCAN_BLOCKS, 256, 0, stream>>>(counts, boff, row_ptr, cursor);
  k_scatter<<<(NE + 255) / 256, 256, 0, stream>>>(grow, gcol, gnv, cursor, epack);

  // fused-conversion GEMM over both matrices -> slice-major XWs (coalesced C)
  k_gemm_fused<<<M2 / 128, 512, 0, stream>>>(features, augf, Wbf, XWs);

  // XCD-sliced SpMM, one phase per launch (per-XCD working set = 3.2MB slice)
  k_spmm_slice<<<SPMM_BLOCKS, 256, 0, stream>>>(row_ptr, epack,
                                                XWs, b1, O);
  k_spmm_slice<<<SPMM_BLOCKS, 256, 0, stream>>>(row_ptr, epack,
                                                XWs + (size_t)NPAIR * MPAD * SLICE_COLS,
                                                b1, O + (size_t)N_NODES * DH);

  // epilogue: S softmax + global partials
  k_post<<<POST_BLOCKS, 256, 0, stream>>>(O, Wt, bt, S, exptot, augtot,
                                          scal + 18, scal + 0);

  // graph stats on assignments
  k_edge<<<512, 256, 0, stream>>>(grow, gcol, gvals, S, scal + 2, scal + 1);

  // final scalar
  k_final<<<1, 256, 0, stream>>>(exptot, augtot, scal, (float*)d_out);
}